// Round 6
// baseline (709.301 us; speedup 1.0000x reference)
//
#include <hip/hip_runtime.h>
#include <cstdint>
#include <cstddef>

// ---------------------------------------------------------------------------
// Problem constants
// ---------------------------------------------------------------------------
constexpr int NB = 256;   // batch
constexpr int NC = 512;   // c_length
constexpr int NL = 16;    // lattice side
constexpr int NFS = 15;   // neighborhood size

#define PARTITIONABLE 1

// ---------------------------------------------------------------------------
// Threefry2x32-20 (JAX-compatible), usable at compile time and on device
// ---------------------------------------------------------------------------
struct TFOut { uint32_t a, b; };

__host__ __device__ constexpr uint32_t rotl32(uint32_t x, int d) {
  return (x << d) | (x >> (32 - d));
}

__host__ __device__ constexpr TFOut tf2x32(uint32_t k0, uint32_t k1,
                                           uint32_t x0, uint32_t x1) {
  uint32_t k2 = k0 ^ k1 ^ 0x1BD11BDAu;
  x0 += k0; x1 += k1;
  const int R0[4] = {13, 15, 26, 6};
  const int R1[4] = {17, 29, 16, 24};
  for (int i = 0; i < 4; i++) { x0 += x1; x1 = rotl32(x1, R0[i]); x1 ^= x0; }
  x0 += k1; x1 += k2 + 1u;
  for (int i = 0; i < 4; i++) { x0 += x1; x1 = rotl32(x1, R1[i]); x1 ^= x0; }
  x0 += k2; x1 += k0 + 2u;
  for (int i = 0; i < 4; i++) { x0 += x1; x1 = rotl32(x1, R0[i]); x1 ^= x0; }
  x0 += k0; x1 += k1 + 3u;
  for (int i = 0; i < 4; i++) { x0 += x1; x1 = rotl32(x1, R1[i]); x1 ^= x0; }
  x0 += k1; x1 += k2 + 4u;
  for (int i = 0; i < 4; i++) { x0 += x1; x1 = rotl32(x1, R0[i]); x1 ^= x0; }
  x0 += k2; x1 += k0 + 5u;
  return TFOut{x0, x1};
}

struct SubKeys { uint32_t v[288]; };

constexpr SubKeys make_subkeys() {
  SubKeys s{};
  uint32_t k0 = 0u, k1 = 1234u;
  for (int t = 0; t < 144; t++) {
#if PARTITIONABLE
    TFOut nk = tf2x32(k0, k1, 0u, 0u);
    TFOut sk = tf2x32(k0, k1, 0u, 1u);
    s.v[2 * t] = sk.a; s.v[2 * t + 1] = sk.b;
    k0 = nk.a; k1 = nk.b;
#else
    TFOut p0 = tf2x32(k0, k1, 0u, 2u);
    TFOut p1 = tf2x32(k0, k1, 1u, 3u);
    s.v[2 * t] = p0.b; s.v[2 * t + 1] = p1.b;
    k0 = p0.a; k1 = p1.a;
#endif
  }
  return s;
}

__constant__ SubKeys SUBKEYS = make_subkeys();

__device__ __forceinline__ float gumbel_from_bits(uint32_t bits) {
  uint32_t ub = (bits >> 9) | 0x3f800000u;
  float f = __uint_as_float(ub) - 1.0f;
  float u = (f == 0.0f) ? 1.17549435e-38f : f;
  float inner = logf(u);
  float outer = logf(-inner);
  return -outer;
}

// ---------------------------------------------------------------------------
// MFMA / bf16 helpers
// ---------------------------------------------------------------------------
typedef __attribute__((ext_vector_type(8))) short bf16x8;
typedef __attribute__((ext_vector_type(4))) float f32x4;

__device__ __forceinline__ void gl2lds16(const unsigned short* g,
                                         unsigned short* l) {
  // async global -> LDS, 16 B/lane; dst is wave-uniform base + lane*16
  __builtin_amdgcn_global_load_lds(
      (const __attribute__((address_space(1))) unsigned int*)g,
      (__attribute__((address_space(3))) unsigned int*)l, 16, 0, 0);
}

__device__ __forceinline__ uint32_t bf_rne(float x) {
  uint32_t u = __float_as_uint(x);
  return (u + 0x7fffu + ((u >> 16) & 1u)) >> 16;
}

// ---------------------------------------------------------------------------
// Kernel 0: init workspace + outputs
// ---------------------------------------------------------------------------
__global__ __launch_bounds__(256) void setup_kernel(
    const float* __restrict__ u_in, const int* __restrict__ v_in,
    float* __restrict__ h0buf, float* __restrict__ cbuf,
    float* __restrict__ u_cur, int* __restrict__ v_cur,
    float* __restrict__ out_soft, float* __restrict__ out_u,
    float* __restrict__ out_v, unsigned int* __restrict__ az) {
  int idx = blockIdx.x * 256 + threadIdx.x;       // [0, 1048576)
  if (idx < 786432) h0buf[idx] = 0.0f;            // 2 parities x [3][NB][NC]
  if (idx < 3 * NB * NC) cbuf[idx] = 0.0f;        // lstm cell state, 3 sectors
  if (idx < 786432) az[idx] = 0u;                 // Ahi+Alo bf16, 2 parities
  if (idx < NB * NL * NL) {
    float uv = u_in[idx];
    int vv = v_in[idx];
    u_cur[idx] = uv;
    v_cur[idx] = vv;
    out_u[idx] = uv;
    out_v[idx] = (float)vv;
  }
  if (idx < NB * NL * NL * 2) out_soft[idx] = 0.0f;
}

// ---------------------------------------------------------------------------
// Kernel 0b (one-time): split whh into bf16 hi/lo pairs.
// grid = 4096 x 256 (= 2048*512 elements)
// ---------------------------------------------------------------------------
__global__ __launch_bounds__(256) void split_w_kernel(
    const float* __restrict__ whh,
    unsigned short* __restrict__ Bhi, unsigned short* __restrict__ Blo) {
  int idx = blockIdx.x * 256 + threadIdx.x;
  float x = whh[idx];
  uint32_t hb = bf_rne(x);
  float lo = x - __uint_as_float(hb << 16);
  Bhi[idx] = (unsigned short)hb;
  Blo[idx] = (unsigned short)bf_rne(lo);
}

// ---------------------------------------------------------------------------
// Kernel 1: WD[n][c] = W1 · (emb[n,1]-emb[n,0]);  A0 = W1 · Σ emb[n,0] + b1
// ---------------------------------------------------------------------------
__global__ __launch_bounds__(256) void wd_kernel(
    const float* __restrict__ emb, const float* __restrict__ w1,
    const float* __restrict__ b1, float* __restrict__ WD,
    float* __restrict__ A0v) {
  __shared__ double dvec[NC];
  int n = blockIdx.x, tid = threadIdx.x;
  for (int k = tid; k < NC; k += 256) {
    if (n < NFS) {
      dvec[k] = (double)emb[(n * 2 + 1) * NC + k] - (double)emb[(n * 2) * NC + k];
    } else {
      double s = 0.0;
      for (int nn = 0; nn < NFS; nn++) s += (double)emb[(nn * 2) * NC + k];
      dvec[k] = s;
    }
  }
  __syncthreads();
  for (int c = tid; c < NC; c += 256) {
    double acc = 0.0;
    const float* wrow = w1 + (size_t)c * NC;
    for (int k = 0; k < NC; k++) acc += dvec[k] * (double)wrow[k];
    if (n < NFS) WD[n * NC + c] = (float)acc;
    else         A0v[c] = (float)(acc + (double)b1[c]);
  }
}

// ---------------------------------------------------------------------------
// Kernel 2: fused LSTM step v3 — discriminating experiment (M1 vs H*).
// Tile 96 rows x 64 gcols (4 gates x 16 c); grid = 8(rt) x 32(ct) = 256
// blocks (1/CU even), 256 thr = 4 waves as 2x2 over the output:
// wave tile 48 rows x 32 gcols, FULL K=512 accumulated in-register
// (no split-K, no cross-wave K-reduction).
// Block-shared double-buffered staging (2 x 20 KB), stage(t+1) issued
// before compute(t) -> per-chunk load latency hidden (T3-minimum pattern).
// L2 read/dispatch 147 -> 81 MB vs r5.  One 26 KB output exchange for
// gate-completeness, then r5's epilogue (wih rows hoisted to registers).
// Swizzle: r3-validated k-slot XOR (linear LDS dest, pre-swizzled source,
// matching XOR on fragment reads).
// ---------------------------------------------------------------------------
__global__ __launch_bounds__(256) void lstm_fused3_kernel(
    const unsigned short* __restrict__ Ah_r, const unsigned short* __restrict__ Al_r,
    unsigned short* __restrict__ Ah_w, unsigned short* __restrict__ Al_w,
    const unsigned short* __restrict__ Bhi, const unsigned short* __restrict__ Blo,
    const float* __restrict__ wih, const float* __restrict__ u_cur,
    const float* __restrict__ bih, const float* __restrict__ bhh,
    float* __restrict__ cbuf, float* __restrict__ h_out, int col0) {
  // Per-buffer slot map (slot = 16 B = 8 shorts), 1280 slots = 20 KB:
  //   slots [0,384):    sAh  (96 rows x 4 k-slots)
  //   slots [384,768):  sAl
  //   slots [768,1024): sBh  (64 gcol-rows x 4 k-slots)
  //   slots [1024,1280): sBl
  __shared__ __align__(16) unsigned short SM[2 * 10240];  // 40 KB
  __shared__ float uvs[96][16];                           // 6 KB

  int bx = blockIdx.x;
  int rt = bx >> 5;                  // [0,8)
  int ct = bx & 31;                  // [0,32)
  int tid = threadIdx.x;
  int w = tid >> 6, lane = tid & 63;
  int l15 = lane & 15, kg = lane >> 4;
  int grow0 = rt * 96;               // global row base (sector*256 + batch)
  int wr0 = (w >> 1) * 48;           // wave row base within tile
  int wg0 = (w & 1) * 32;            // wave gcol base within tile

  // ---- stage uv (exact fp32) for the epilogue's uv·wih term ----
#pragma unroll
  for (int q = 0; q < 6; q++) {
    int idx = q * 256 + tid;         // [0,1536)
    int r = idx >> 4, nn = idx & 15;
    int grow = grow0 + r;
    int s = grow >> 8, b = grow & 255;
    uvs[r][nn] =
        u_cur[b * 256 + (s * 4 + (nn >> 2)) * 16 + col0 + (nn & 3)];
  }

  // ---- cooperative staging of one BK=32 chunk into buffer `bufsel` ----
  auto STAGE = [&](int bufsel, int k0) {
    unsigned short* base = SM + bufsel * 10240;
#pragma unroll
    for (int q = 0; q < 5; q++) {
      int g = w + 4 * q;             // wave-uniform group id [0,20)
      int s = g * 64 + lane;         // slot [0,1280)
      const unsigned short* src;
      if (s < 768) {                 // A hi/lo (group-aligned: 384%64==0)
        int a = (s >= 384) ? 1 : 0;
        int rs = s - a * 384;
        int r = rs >> 2, kq = rs & 3;
        int kqs = kq ^ ((r >> 1) & 3);
        size_t so = (size_t)(grow0 + r) * 512 + k0 + kqs * 8;
        src = (a ? Al_r : Ah_r) + so;
      } else {                       // B hi/lo
        int a = (s >= 1024) ? 1 : 0;
        int rs = s - 768 - a * 256;
        int rr = rs >> 2, kq = rs & 3;
        int kqs = kq ^ ((rr >> 1) & 3);
        int n = (rr >> 4) * 512 + ct * 16 + (rr & 15);  // gate*512 + c
        size_t so = (size_t)n * 512 + k0 + kqs * 8;
        src = (a ? Blo : Bhi) + so;
      }
      gl2lds16(src, base + (size_t)g * 512);
    }
  };

  f32x4 acc[3][2];
#pragma unroll
  for (int i = 0; i < 3; i++)
#pragma unroll
    for (int j = 0; j < 2; j++) acc[i][j] = (f32x4){0.f, 0.f, 0.f, 0.f};

  STAGE(0, 0);
  __syncthreads();                   // vmcnt(0) drained: buf0 ready

  // ---- main K loop: 16 chunks of BK=32, double-buffered ----
  for (int t = 0; t < 16; t++) {
    int cur = t & 1;
    if (t < 15) STAGE(cur ^ 1, (t + 1) * 32);
    unsigned short* base = SM + cur * 10240;
    bf16x8 ah[3], al[3], bh[2], bl[2];
#pragma unroll
    for (int i = 0; i < 3; i++) {
      int r = wr0 + i * 16 + l15;
      int off = r * 32 + (kg ^ ((r >> 1) & 3)) * 8;
      ah[i] = *(const bf16x8*)&base[off];
      al[i] = *(const bf16x8*)&base[3072 + off];
    }
#pragma unroll
    for (int j = 0; j < 2; j++) {
      int rr = wg0 + j * 16 + l15;
      int off = rr * 32 + (kg ^ ((rr >> 1) & 3)) * 8;
      bh[j] = *(const bf16x8*)&base[6144 + off];
      bl[j] = *(const bf16x8*)&base[8192 + off];
    }
#pragma unroll
    for (int i = 0; i < 3; i++)
#pragma unroll
      for (int j = 0; j < 2; j++) {
        acc[i][j] = __builtin_amdgcn_mfma_f32_16x16x32_bf16(ah[i], bh[j],
                                                            acc[i][j], 0, 0, 0);
        acc[i][j] = __builtin_amdgcn_mfma_f32_16x16x32_bf16(ah[i], bl[j],
                                                            acc[i][j], 0, 0, 0);
        acc[i][j] = __builtin_amdgcn_mfma_f32_16x16x32_bf16(al[i], bh[j],
                                                            acc[i][j], 0, 0, 0);
      }
    __syncthreads();   // drains vmcnt: stage(t+1) landed; buf reads done
  }

  // ---- hoist per-thread constants (cglob = ct*16 + tid&15 fixed) ----
  int c = tid & 15;
  int cglob = ct * 16 + c;
  float bi_[4], bh_[4];
  float wihr[4][16];
#pragma unroll
  for (int g = 0; g < 4; g++) {
    bi_[g] = bih[g * 512 + cglob];
    bh_[g] = bhh[g * 512 + cglob];
    const float4* wr = (const float4*)(wih + (size_t)(g * 512 + cglob) * 16);
#pragma unroll
    for (int f = 0; f < 4; f++) {
      float4 v4 = wr[f];
      wihr[g][f * 4 + 0] = v4.x;
      wihr[g][f * 4 + 1] = v4.y;
      wihr[g][f * 4 + 2] = v4.z;
      wihr[g][f * 4 + 3] = v4.w;
    }
  }

  // ---- output exchange for gate-completeness: [96][68] f32, aliases SM ----
  float* ex = (float*)SM;            // 96*68*4 = 26112 B < 40960 B
#pragma unroll
  for (int i = 0; i < 3; i++)
#pragma unroll
    for (int j = 0; j < 2; j++)
#pragma unroll
      for (int rr = 0; rr < 4; rr++) {
        int row = wr0 + i * 16 + kg * 4 + rr;   // m89 C/D layout
        int gcol = wg0 + j * 16 + l15;
        ex[row * 68 + gcol] = acc[i][j][rr];
      }
  __syncthreads();

  // ---- epilogue: 6 (row, c) outputs per thread ----
#pragma unroll
  for (int q = 0; q < 6; q++) {
    int row = q * 16 + (tid >> 4);             // [0,96)
    int grow = grow0 + row;
    float uvr[16];
#pragma unroll
    for (int nn = 0; nn < 16; nn++) uvr[nn] = uvs[row][nn];
    float gv[4];
#pragma unroll
    for (int g = 0; g < 4; g++) {
      float v = ex[row * 68 + g * 16 + c];
#pragma unroll
      for (int nn = 0; nn < 16; nn++) v = fmaf(uvr[nn], wihr[g][nn], v);
      gv[g] = v + bi_[g] + bh_[g];
    }
    size_t off = (size_t)grow * NC + cglob;
    float c_old = cbuf[off];
    float sig_i = 1.0f / (1.0f + expf(-gv[0]));
    float sig_f = 1.0f / (1.0f + expf(-gv[1]));
    float tg    = tanhf(gv[2]);
    float sig_o = 1.0f / (1.0f + expf(-gv[3]));
    float cn = sig_f * c_old + sig_i * tg;
    float hn = sig_o * tanhf(cn);
    cbuf[off] = cn;
    h_out[off] = hn;
    uint32_t hb = bf_rne(hn);
    float lo = hn - __uint_as_float(hb << 16);
    Ah_w[off] = (unsigned short)hb;
    Al_w[off] = (unsigned short)bf_rne(lo);
  }
}

// ---------------------------------------------------------------------------
// Kernel 3: Hpart[ks][b][c] partials of H = W1 · h0 (fp32 — kept exact).
// grid = 8(ks,K=64 each) * 4(bt) * 8(ct) = 256 blocks, 256 threads.
// ---------------------------------------------------------------------------
__global__ __launch_bounds__(256) void w1h0_kernel(
    const float* __restrict__ h_in,   // [NB][NC] slice for (parity, s=i)
    const float* __restrict__ w1, float* __restrict__ Hpart) {
  int bx = blockIdx.x;
  int ks = bx >> 5;
  int bt = (bx >> 3) & 3;
  int ct = bx & 7;
  int tid = threadIdx.x, tn = tid & 15, tb = tid >> 4;

  __shared__ float hs[64][36];
  __shared__ float wt[64][36];
  float acc[4][4] = {};
  const float* hbase = h_in + (size_t)(bt * 64) * NC;

  for (int kc = 0; kc < 2; kc++) {
    int k0 = ks * 64 + kc * 32;
    __syncthreads();
    for (int t = 0; t < 2; t++) {
      int idx = tid + t * 256;
      int row = idx >> 3, kk4 = idx & 7;
      *(float4*)&hs[row][kk4 * 4] =
          *(const float4*)(hbase + (size_t)row * NC + k0 + kk4 * 4);
      int wrow = ct * 64 + row;
      *(float4*)&wt[row][kk4 * 4] =
          *(const float4*)(w1 + (size_t)wrow * NC + k0 + kk4 * 4);
    }
    __syncthreads();
#pragma unroll
    for (int kk4 = 0; kk4 < 8; kk4++) {
      float4 hv[4], wv[4];
#pragma unroll
      for (int i = 0; i < 4; i++) hv[i] = *(float4*)&hs[tb * 4 + i][kk4 * 4];
#pragma unroll
      for (int j = 0; j < 4; j++) wv[j] = *(float4*)&wt[tn + 16 * j][kk4 * 4];
#pragma unroll
      for (int i = 0; i < 4; i++)
#pragma unroll
        for (int j = 0; j < 4; j++)
          acc[i][j] += hv[i].x * wv[j].x + hv[i].y * wv[j].y +
                       hv[i].z * wv[j].z + hv[i].w * wv[j].w;
    }
  }
#pragma unroll
  for (int i = 0; i < 4; i++) {
    int b = bt * 64 + tb * 4 + i;
#pragma unroll
    for (int j = 0; j < 4; j++) {
      int cidx = ct * 64 + tn + 16 * j;
      Hpart[((size_t)ks * NB + b) * NC + cidx] = acc[i][j];
    }
  }
}

// ---------------------------------------------------------------------------
// Kernel 4: 16-pixel autoregressive block (register version, 8-partial sum).
// ---------------------------------------------------------------------------
__global__ __launch_bounds__(64) void pixel_kernel(
    const float* __restrict__ WD, const float* __restrict__ A0v,
    const float* __restrict__ Hpart, const float* __restrict__ w2,
    const float* __restrict__ b2, float* __restrict__ u_cur,
    int* __restrict__ v_cur, float* __restrict__ out_soft,
    float* __restrict__ out_u, float* __restrict__ out_v,
    int si, int sj, int t_base) {
  int b = blockIdx.x, lane = threadIdx.x;
  __shared__ float gum[32];

  int widx = (lane < 49) ? lane : 48;
  int vv = v_cur[b * 256 + (si + 1 + widx / 7) * 16 + (sj + 1 + widx % 7)];
  unsigned long long mask = __ballot((lane < 49) && (vv != 0));

  if (lane < 32) {
    int t = t_base + (lane >> 1);
    uint32_t sk0 = SUBKEYS.v[2 * t], sk1 = SUBKEYS.v[2 * t + 1];
    uint32_t bits;
#if PARTITIONABLE
    TFOut o = tf2x32(sk0, sk1, 0u, (uint32_t)(2 * b + (lane & 1)));
    bits = o.a ^ o.b;
#else
    uint32_t f = (uint32_t)(2 * b + (lane & 1));
    if (f < 256u) { TFOut o = tf2x32(sk0, sk1, f, f + 256u); bits = o.a; }
    else          { TFOut o = tf2x32(sk0, sk1, f - 256u, f); bits = o.b; }
#endif
    gum[lane] = gumbel_from_bits(bits);
  }

  float wdreg[NFS][8];
#pragma unroll
  for (int n = 0; n < NFS; n++)
#pragma unroll
    for (int r = 0; r < 8; r++) wdreg[n][r] = WD[n * NC + lane + 64 * r];

  float w2r0[8], w2r1[8];
#pragma unroll
  for (int r = 0; r < 8; r++) {
    w2r0[r] = w2[lane + 64 * r];
    w2r1[r] = w2[NC + lane + 64 * r];
  }
  double b20 = (double)b2[0], b21 = (double)b2[1];

  float base[8];
#pragma unroll
  for (int r = 0; r < 8; r++) {
    int c = lane + 64 * r;
    float v = A0v[c];
#pragma unroll
    for (int ks = 0; ks < 8; ks++) v += Hpart[((size_t)ks * NB + b) * NC + c];
    base[r] = v;
  }
  __syncthreads();

#pragma unroll 1
  for (int ii = 0; ii < 4; ii++) {
#pragma unroll 1
    for (int jj = 0; jj < 4; jj++) {
      int bofs = ii * 7 + jj;
      float acc[8];
#pragma unroll
      for (int r = 0; r < 8; r++) acc[r] = base[r];
#pragma unroll
      for (int n = 0; n < NFS; n++) {
        const int OFF = (n / 4) * 7 + (n % 4);
        float pf = (float)((unsigned)((mask >> (bofs + OFF)) & 1ull));
#pragma unroll
        for (int r = 0; r < 8; r++) acc[r] = fmaf(pf, wdreg[n][r], acc[r]);
      }
      double d0 = 0.0, d1 = 0.0;
#pragma unroll
      for (int r = 0; r < 8; r++) {
        float z = fmaxf(acc[r], 0.0f);
        d0 += (double)z * (double)w2r0[r];
        d1 += (double)z * (double)w2r1[r];
      }
#pragma unroll
      for (int off = 32; off > 0; off >>= 1) {
        d0 += __shfl_xor(d0, off, 64);
        d1 += __shfl_xor(d1, off, 64);
      }
      float r0 = (float)(d0 + b20);
      float r1 = (float)(d1 + b21);
      float m = fmaxf(r0, r1);
      float s0 = r0 - m, s1 = r1 - m;
      float lse = logf(expf(s0) + expf(s1));
      float l0 = s0 - lse, l1 = s1 - lse;
      int pidx = ii * 4 + jj;
      float a0 = l0 + gum[2 * pidx];
      float a1 = l1 + gum[2 * pidx + 1];
      int samp = (a1 > a0) ? 1 : 0;
      int tbit = bofs + 24;
      mask = (mask & ~(1ull << tbit)) | ((unsigned long long)samp << tbit);
      if (lane == 0) {
        int pr = si + ii + 4, pc = sj + jj + 4;
        size_t so = ((size_t)(b * 16 + pr) * 16 + pc) * 2;
        out_soft[so] = l0;
        out_soft[so + 1] = l1;
        int po = b * 256 + pr * 16 + pc;
        float fs = (float)samp;
        u_cur[po] = fs;
        v_cur[po] = samp;
        out_u[po] = fs;
        out_v[po] = fs;
      }
    }
  }
}

// ---------------------------------------------------------------------------
// Host-side launch sequence
// ---------------------------------------------------------------------------
extern "C" void kernel_launch(void* const* d_in, const int* in_sizes, int n_in,
                              void* d_out, int out_size, void* d_ws,
                              size_t ws_size, hipStream_t stream) {
  (void)in_sizes; (void)n_in; (void)out_size; (void)ws_size;
  const float* u_in = (const float*)d_in[0];
  const int*   v_in = (const int*)d_in[1];
  const float* emb  = (const float*)d_in[2];
  const float* w1   = (const float*)d_in[3];
  const float* b1   = (const float*)d_in[4];
  const float* w2   = (const float*)d_in[5];
  const float* b2   = (const float*)d_in[6];
  const float* wih  = (const float*)d_in[7];
  const float* whh  = (const float*)d_in[8];
  const float* bih  = (const float*)d_in[9];
  const float* bhh  = (const float*)d_in[10];

  float* ws = (float*)d_ws;
  const size_t HP = (size_t)3 * NB * NC;           // 393216: h parity stride
  float* h0buf = ws;                               // [2][3][NB][NC]
  float* cbuf  = h0buf + 2 * HP;                   // [3][NB][NC]
  float* Hpart = cbuf + (size_t)3 * NB * NC;       // [8][NB][NC]
  float* WDp   = Hpart + (size_t)8 * NB * NC;      // [15][NC]
  float* A0v   = WDp + NFS * NC;                   // [NC]
  float* u_cur = A0v + NC;                         // [NB][16][16]
  int*   v_cur = (int*)(u_cur + NB * NL * NL);     // [NB][16][16]
  unsigned short* Ahi = (unsigned short*)(v_cur + NB * NL * NL); // [2][768][512]
  unsigned short* Alo = Ahi + (size_t)2 * 768 * 512;             // [2][768][512]
  unsigned short* Bhi = Alo + (size_t)2 * 768 * 512;             // [2048][512]
  unsigned short* Blo = Bhi + (size_t)2048 * 512;                // [2048][512]
  const size_t APAR = (size_t)768 * 512;           // parity stride (shorts)

  float* out_soft = (float*)d_out;                 // [NB][16][16][2]
  float* out_u = out_soft + NB * NL * NL * 2;      // [NB][16][16]
  float* out_v = out_u + NB * NL * NL;             // [NB][16][16]

  setup_kernel<<<dim3(4096), dim3(256), 0, stream>>>(
      u_in, v_in, h0buf, cbuf, u_cur, v_cur, out_soft, out_u, out_v,
      (unsigned int*)Ahi);
  split_w_kernel<<<dim3(4096), dim3(256), 0, stream>>>(whh, Bhi, Blo);
  wd_kernel<<<dim3(16), dim3(256), 0, stream>>>(emb, w1, b1, WDp, A0v);

  for (int k = 0; k < 9; k++) {
    if (k > 0) {
      int e = k - 1;
      int col0 = (e % 3 == 0) ? 4 : ((e % 3 == 1) ? 8 : 0);
      int rp = e & 1, wp = rp ^ 1;
      lstm_fused3_kernel<<<dim3(256), dim3(256), 0, stream>>>(
          Ahi + (size_t)rp * APAR, Alo + (size_t)rp * APAR,
          Ahi + (size_t)wp * APAR, Alo + (size_t)wp * APAR,
          Bhi, Blo, wih, u_cur, bih, bhh, cbuf,
          h0buf + (size_t)wp * HP, col0);
    }
    w1h0_kernel<<<dim3(256), dim3(256), 0, stream>>>(
        h0buf + (size_t)(k & 1) * HP + (size_t)(k / 3) * NB * NC, w1, Hpart);
    pixel_kernel<<<dim3(256), dim3(64), 0, stream>>>(
        WDp, A0v, Hpart, w2, b2, u_cur, v_cur, out_soft, out_u, out_v,
        (k / 3) * 4, (k % 3) * 4, k * 16);
  }
}

// Round 7
// 542.709 us; speedup vs baseline: 1.3070x; 1.3070x over previous
//
#include <hip/hip_runtime.h>
#include <cstdint>
#include <cstddef>

// ---------------------------------------------------------------------------
// Problem constants
// ---------------------------------------------------------------------------
constexpr int NB = 256;   // batch
constexpr int NC = 512;   // c_length
constexpr int NL = 16;    // lattice side
constexpr int NFS = 15;   // neighborhood size

#define PARTITIONABLE 1

// ---------------------------------------------------------------------------
// Threefry2x32-20 (JAX-compatible), usable at compile time and on device
// ---------------------------------------------------------------------------
struct TFOut { uint32_t a, b; };

__host__ __device__ constexpr uint32_t rotl32(uint32_t x, int d) {
  return (x << d) | (x >> (32 - d));
}

__host__ __device__ constexpr TFOut tf2x32(uint32_t k0, uint32_t k1,
                                           uint32_t x0, uint32_t x1) {
  uint32_t k2 = k0 ^ k1 ^ 0x1BD11BDAu;
  x0 += k0; x1 += k1;
  const int R0[4] = {13, 15, 26, 6};
  const int R1[4] = {17, 29, 16, 24};
  for (int i = 0; i < 4; i++) { x0 += x1; x1 = rotl32(x1, R0[i]); x1 ^= x0; }
  x0 += k1; x1 += k2 + 1u;
  for (int i = 0; i < 4; i++) { x0 += x1; x1 = rotl32(x1, R1[i]); x1 ^= x0; }
  x0 += k2; x1 += k0 + 2u;
  for (int i = 0; i < 4; i++) { x0 += x1; x1 = rotl32(x1, R0[i]); x1 ^= x0; }
  x0 += k0; x1 += k1 + 3u;
  for (int i = 0; i < 4; i++) { x0 += x1; x1 = rotl32(x1, R1[i]); x1 ^= x0; }
  x0 += k1; x1 += k2 + 4u;
  for (int i = 0; i < 4; i++) { x0 += x1; x1 = rotl32(x1, R0[i]); x1 ^= x0; }
  x0 += k2; x1 += k0 + 5u;
  return TFOut{x0, x1};
}

struct SubKeys { uint32_t v[288]; };

constexpr SubKeys make_subkeys() {
  SubKeys s{};
  uint32_t k0 = 0u, k1 = 1234u;
  for (int t = 0; t < 144; t++) {
#if PARTITIONABLE
    TFOut nk = tf2x32(k0, k1, 0u, 0u);
    TFOut sk = tf2x32(k0, k1, 0u, 1u);
    s.v[2 * t] = sk.a; s.v[2 * t + 1] = sk.b;
    k0 = nk.a; k1 = nk.b;
#else
    TFOut p0 = tf2x32(k0, k1, 0u, 2u);
    TFOut p1 = tf2x32(k0, k1, 1u, 3u);
    s.v[2 * t] = p0.b; s.v[2 * t + 1] = p1.b;
    k0 = p0.a; k1 = p1.a;
#endif
  }
  return s;
}

__constant__ SubKeys SUBKEYS = make_subkeys();

__device__ __forceinline__ float gumbel_from_bits(uint32_t bits) {
  uint32_t ub = (bits >> 9) | 0x3f800000u;
  float f = __uint_as_float(ub) - 1.0f;
  float u = (f == 0.0f) ? 1.17549435e-38f : f;
  float inner = logf(u);
  float outer = logf(-inner);
  return -outer;
}

// ---------------------------------------------------------------------------
// MFMA / bf16 helpers
// ---------------------------------------------------------------------------
typedef __attribute__((ext_vector_type(8))) short bf16x8;
typedef __attribute__((ext_vector_type(4))) float f32x4;

__device__ __forceinline__ uint32_t bf_rne(float x) {
  uint32_t u = __float_as_uint(x);
  return (u + 0x7fffu + ((u >> 16) & 1u)) >> 16;
}

// ---------------------------------------------------------------------------
// Kernel 0: init workspace + outputs
// ---------------------------------------------------------------------------
__global__ __launch_bounds__(256) void setup_kernel(
    const float* __restrict__ u_in, const int* __restrict__ v_in,
    float* __restrict__ h0buf, float* __restrict__ cbuf,
    float* __restrict__ u_cur, int* __restrict__ v_cur,
    float* __restrict__ out_soft, float* __restrict__ out_u,
    float* __restrict__ out_v, unsigned int* __restrict__ az) {
  int idx = blockIdx.x * 256 + threadIdx.x;       // [0, 1048576)
  if (idx < 786432) h0buf[idx] = 0.0f;            // 2 parities x [3][NB][NC]
  if (idx < 3 * NB * NC) cbuf[idx] = 0.0f;        // lstm cell state, 3 sectors
  if (idx < 786432) az[idx] = 0u;                 // Ahi+Alo bf16, 2 parities
  if (idx < NB * NL * NL) {
    float uv = u_in[idx];
    int vv = v_in[idx];
    u_cur[idx] = uv;
    v_cur[idx] = vv;
    out_u[idx] = uv;
    out_v[idx] = (float)vv;
  }
  if (idx < NB * NL * NL * 2) out_soft[idx] = 0.0f;
}

// ---------------------------------------------------------------------------
// Kernel 0b (one-time): split whh into bf16 hi/lo pairs.
// grid = 4096 x 256 (= 2048*512 elements)
// ---------------------------------------------------------------------------
__global__ __launch_bounds__(256) void split_w_kernel(
    const float* __restrict__ whh,
    unsigned short* __restrict__ Bhi, unsigned short* __restrict__ Blo) {
  int idx = blockIdx.x * 256 + threadIdx.x;
  float x = whh[idx];
  uint32_t hb = bf_rne(x);
  float lo = x - __uint_as_float(hb << 16);
  Bhi[idx] = (unsigned short)hb;
  Blo[idx] = (unsigned short)bf_rne(lo);
}

// ---------------------------------------------------------------------------
// Kernel 1: WD[n][c] = W1 · (emb[n,1]-emb[n,0]);  A0 = W1 · Σ emb[n,0] + b1
// ---------------------------------------------------------------------------
__global__ __launch_bounds__(256) void wd_kernel(
    const float* __restrict__ emb, const float* __restrict__ w1,
    const float* __restrict__ b1, float* __restrict__ WD,
    float* __restrict__ A0v) {
  __shared__ double dvec[NC];
  int n = blockIdx.x, tid = threadIdx.x;
  for (int k = tid; k < NC; k += 256) {
    if (n < NFS) {
      dvec[k] = (double)emb[(n * 2 + 1) * NC + k] - (double)emb[(n * 2) * NC + k];
    } else {
      double s = 0.0;
      for (int nn = 0; nn < NFS; nn++) s += (double)emb[(nn * 2) * NC + k];
      dvec[k] = s;
    }
  }
  __syncthreads();
  for (int c = tid; c < NC; c += 256) {
    double acc = 0.0;
    const float* wrow = w1 + (size_t)c * NC;
    for (int k = 0; k < NC; k++) acc += dvec[k] * (double)wrow[k];
    if (n < NFS) WD[n * NC + c] = (float)acc;
    else         A0v[c] = (float)(acc + (double)b1[c]);
  }
}

// ---------------------------------------------------------------------------
// Kernel 2: fused LSTM step, register-direct operand loads (r7).
// Geometry identical to r5-fused2: grid = 24(rt) x 32(ct) = 768 blocks
// (3/CU even), 256 thr = 4 waves; wave w owns K-slice [w*128, w*128+128)
// in 4 chunks of BK=32; wave-tile 32 rows x 64 gcols (gate-complete).
// KEY CHANGE vs r5: NO LDS staging, NO K-loop barriers. Each wave loads
// its MFMA fragments directly global->VGPR (bf16x8 = 16B/lane covering
// 16 full 64B lines per load). Compiler schedules per-dependency
// s_waitcnt vmcnt(N); 12 waves/CU provide memory-level parallelism.
// A (1.5 MB) and B (4 MB) are L2-resident.
// Cross-wave K-reduction via padded LDS (unchanged, bit-identical order);
// epilogue (bias + exact-fp32 uv·wih + LSTM nonlinearity) unchanged.
// ---------------------------------------------------------------------------
__global__ __launch_bounds__(256, 3) void lstm_fused2r_kernel(
    const unsigned short* __restrict__ Ah_r, const unsigned short* __restrict__ Al_r,
    unsigned short* __restrict__ Ah_w, unsigned short* __restrict__ Al_w,
    const unsigned short* __restrict__ Bhi, const unsigned short* __restrict__ Blo,
    const float* __restrict__ wih, const float* __restrict__ u_cur,
    const float* __restrict__ bih, const float* __restrict__ bhh,
    float* __restrict__ cbuf, float* __restrict__ h_out, int col0) {
  __shared__ float red[512 * 17];      // 34.8 KB cross-wave reduction buffer
  __shared__ float uvs[32][16];        // 2 KB

  int bx = blockIdx.x;
  int rt = bx >> 5;                    // [0,24)
  int ct = bx & 31;                    // [0,32)
  int tid = threadIdx.x;
  int w = tid >> 6, lane = tid & 63;
  int l15 = lane & 15, kg = lane >> 4;
  int grow0 = rt * 32;                 // global row base (sector*256 + batch)
  int s = rt >> 3;                     // sector index
  int b0 = (rt & 7) * 32;              // batch base

  // stage uv (exact fp32) for the epilogue's uv·wih term
  {
    int idx = tid;
    for (int t = 0; t < 2; t++, idx += 256) {
      int r = idx >> 4, nn = idx & 15;
      uvs[r][nn] =
          u_cur[(b0 + r) * 256 + (s * 4 + (nn >> 2)) * 16 + col0 + (nn & 3)];
    }
  }

  f32x4 acc[2][4];
#pragma unroll
  for (int i = 0; i < 2; i++)
#pragma unroll
    for (int j = 0; j < 4; j++) acc[i][j] = (f32x4){0.f, 0.f, 0.f, 0.f};

  // per-lane fragment base offsets (in shorts)
  size_t aoff = (size_t)(grow0 + l15) * 512 + kg * 8;        // + i*16*512 + k
  size_t boff = (size_t)(ct * 16 + l15) * 512 + kg * 8;      // + j*262144 + k

  // ---- main K loop: 4 chunks of BK=32, fragments direct from global ----
#pragma unroll
  for (int kc = 0; kc < 4; kc++) {
    int k0 = w * 128 + kc * 32;
    bf16x8 ah[2], al[2], bh[4], bl[4];
#pragma unroll
    for (int i = 0; i < 2; i++) {
      size_t o = aoff + (size_t)i * 16 * 512 + k0;
      ah[i] = *(const bf16x8*)&Ah_r[o];
      al[i] = *(const bf16x8*)&Al_r[o];
    }
#pragma unroll
    for (int j = 0; j < 4; j++) {
      size_t o = boff + (size_t)j * 262144 + k0;
      bh[j] = *(const bf16x8*)&Bhi[o];
      bl[j] = *(const bf16x8*)&Blo[o];
    }
#pragma unroll
    for (int j = 0; j < 4; j++)
#pragma unroll
      for (int i = 0; i < 2; i++) {
        acc[i][j] = __builtin_amdgcn_mfma_f32_16x16x32_bf16(ah[i], bh[j],
                                                            acc[i][j], 0, 0, 0);
        acc[i][j] = __builtin_amdgcn_mfma_f32_16x16x32_bf16(ah[i], bl[j],
                                                            acc[i][j], 0, 0, 0);
        acc[i][j] = __builtin_amdgcn_mfma_f32_16x16x32_bf16(al[i], bh[j],
                                                            acc[i][j], 0, 0, 0);
      }
  }

  // ---- cross-wave reduction through LDS (padded, conflict-free) ----
#pragma unroll
  for (int i = 0; i < 2; i++)
#pragma unroll
    for (int g = 0; g < 4; g++)
#pragma unroll
      for (int rr = 0; rr < 4; rr++) {
        int row = i * 16 + kg * 4 + rr;    // m89 C/D layout
        red[((w * 4 + g) * 32 + row) * 17 + l15] = acc[i][g][rr];
      }
  __syncthreads();

  // ---- epilogue: 2 rows per thread covers the full 32x16 tile ----
  int rbase = tid >> 4, c = tid & 15;      // rbase in [0,16)
  int cglob = ct * 16 + c;
  float bi_[4], bh_[4];
#pragma unroll
  for (int g = 0; g < 4; g++) {
    bi_[g] = bih[g * 512 + cglob];
    bh_[g] = bhh[g * 512 + cglob];
  }
#pragma unroll
  for (int rh = 0; rh < 2; rh++) {
    int row = rh * 16 + rbase;               // [0,32)
    int grow = grow0 + row;
    float uvr[16];
#pragma unroll
    for (int nn = 0; nn < 16; nn++) uvr[nn] = uvs[row][nn];
    float gv[4];
#pragma unroll
    for (int g = 0; g < 4; g++) {
      float v = 0.0f;
#pragma unroll
      for (int ww = 0; ww < 4; ww++)
        v += red[((ww * 4 + g) * 32 + row) * 17 + c];
      const float* wr = wih + (size_t)(g * 512 + cglob) * 16;
#pragma unroll
      for (int nn = 0; nn < 16; nn++) v = fmaf(uvr[nn], wr[nn], v);
      gv[g] = v + bi_[g] + bh_[g];
    }
    size_t off = (size_t)grow * NC + cglob;
    float c_old = cbuf[off];
    float sig_i = 1.0f / (1.0f + expf(-gv[0]));
    float sig_f = 1.0f / (1.0f + expf(-gv[1]));
    float tg    = tanhf(gv[2]);
    float sig_o = 1.0f / (1.0f + expf(-gv[3]));
    float cn = sig_f * c_old + sig_i * tg;
    float hn = sig_o * tanhf(cn);
    cbuf[off] = cn;
    h_out[off] = hn;
    uint32_t hb = bf_rne(hn);
    float lo = hn - __uint_as_float(hb << 16);
    Ah_w[off] = (unsigned short)hb;
    Al_w[off] = (unsigned short)bf_rne(lo);
  }
}

// ---------------------------------------------------------------------------
// Kernel 3: Hpart[ks][b][c] partials of H = W1 · h0 (fp32 — kept exact).
// grid = 8(ks,K=64 each) * 4(bt) * 8(ct) = 256 blocks, 256 threads.
// ---------------------------------------------------------------------------
__global__ __launch_bounds__(256) void w1h0_kernel(
    const float* __restrict__ h_in,   // [NB][NC] slice for (parity, s=i)
    const float* __restrict__ w1, float* __restrict__ Hpart) {
  int bx = blockIdx.x;
  int ks = bx >> 5;
  int bt = (bx >> 3) & 3;
  int ct = bx & 7;
  int tid = threadIdx.x, tn = tid & 15, tb = tid >> 4;

  __shared__ float hs[64][36];
  __shared__ float wt[64][36];
  float acc[4][4] = {};
  const float* hbase = h_in + (size_t)(bt * 64) * NC;

  for (int kc = 0; kc < 2; kc++) {
    int k0 = ks * 64 + kc * 32;
    __syncthreads();
    for (int t = 0; t < 2; t++) {
      int idx = tid + t * 256;
      int row = idx >> 3, kk4 = idx & 7;
      *(float4*)&hs[row][kk4 * 4] =
          *(const float4*)(hbase + (size_t)row * NC + k0 + kk4 * 4);
      int wrow = ct * 64 + row;
      *(float4*)&wt[row][kk4 * 4] =
          *(const float4*)(w1 + (size_t)wrow * NC + k0 + kk4 * 4);
    }
    __syncthreads();
#pragma unroll
    for (int kk4 = 0; kk4 < 8; kk4++) {
      float4 hv[4], wv[4];
#pragma unroll
      for (int i = 0; i < 4; i++) hv[i] = *(float4*)&hs[tb * 4 + i][kk4 * 4];
#pragma unroll
      for (int j = 0; j < 4; j++) wv[j] = *(float4*)&wt[tn + 16 * j][kk4 * 4];
#pragma unroll
      for (int i = 0; i < 4; i++)
#pragma unroll
        for (int j = 0; j < 4; j++)
          acc[i][j] += hv[i].x * wv[j].x + hv[i].y * wv[j].y +
                       hv[i].z * wv[j].z + hv[i].w * wv[j].w;
    }
  }
#pragma unroll
  for (int i = 0; i < 4; i++) {
    int b = bt * 64 + tb * 4 + i;
#pragma unroll
    for (int j = 0; j < 4; j++) {
      int cidx = ct * 64 + tn + 16 * j;
      Hpart[((size_t)ks * NB + b) * NC + cidx] = acc[i][j];
    }
  }
}

// ---------------------------------------------------------------------------
// Kernel 4: 16-pixel autoregressive block (register version, 8-partial sum).
// ---------------------------------------------------------------------------
__global__ __launch_bounds__(64) void pixel_kernel(
    const float* __restrict__ WD, const float* __restrict__ A0v,
    const float* __restrict__ Hpart, const float* __restrict__ w2,
    const float* __restrict__ b2, float* __restrict__ u_cur,
    int* __restrict__ v_cur, float* __restrict__ out_soft,
    float* __restrict__ out_u, float* __restrict__ out_v,
    int si, int sj, int t_base) {
  int b = blockIdx.x, lane = threadIdx.x;
  __shared__ float gum[32];

  int widx = (lane < 49) ? lane : 48;
  int vv = v_cur[b * 256 + (si + 1 + widx / 7) * 16 + (sj + 1 + widx % 7)];
  unsigned long long mask = __ballot((lane < 49) && (vv != 0));

  if (lane < 32) {
    int t = t_base + (lane >> 1);
    uint32_t sk0 = SUBKEYS.v[2 * t], sk1 = SUBKEYS.v[2 * t + 1];
    uint32_t bits;
#if PARTITIONABLE
    TFOut o = tf2x32(sk0, sk1, 0u, (uint32_t)(2 * b + (lane & 1)));
    bits = o.a ^ o.b;
#else
    uint32_t f = (uint32_t)(2 * b + (lane & 1));
    if (f < 256u) { TFOut o = tf2x32(sk0, sk1, f, f + 256u); bits = o.a; }
    else          { TFOut o = tf2x32(sk0, sk1, f - 256u, f); bits = o.b; }
#endif
    gum[lane] = gumbel_from_bits(bits);
  }

  float wdreg[NFS][8];
#pragma unroll
  for (int n = 0; n < NFS; n++)
#pragma unroll
    for (int r = 0; r < 8; r++) wdreg[n][r] = WD[n * NC + lane + 64 * r];

  float w2r0[8], w2r1[8];
#pragma unroll
  for (int r = 0; r < 8; r++) {
    w2r0[r] = w2[lane + 64 * r];
    w2r1[r] = w2[NC + lane + 64 * r];
  }
  double b20 = (double)b2[0], b21 = (double)b2[1];

  float base[8];
#pragma unroll
  for (int r = 0; r < 8; r++) {
    int c = lane + 64 * r;
    float v = A0v[c];
#pragma unroll
    for (int ks = 0; ks < 8; ks++) v += Hpart[((size_t)ks * NB + b) * NC + c];
    base[r] = v;
  }
  __syncthreads();

#pragma unroll 1
  for (int ii = 0; ii < 4; ii++) {
#pragma unroll 1
    for (int jj = 0; jj < 4; jj++) {
      int bofs = ii * 7 + jj;
      float acc[8];
#pragma unroll
      for (int r = 0; r < 8; r++) acc[r] = base[r];
#pragma unroll
      for (int n = 0; n < NFS; n++) {
        const int OFF = (n / 4) * 7 + (n % 4);
        float pf = (float)((unsigned)((mask >> (bofs + OFF)) & 1ull));
#pragma unroll
        for (int r = 0; r < 8; r++) acc[r] = fmaf(pf, wdreg[n][r], acc[r]);
      }
      double d0 = 0.0, d1 = 0.0;
#pragma unroll
      for (int r = 0; r < 8; r++) {
        float z = fmaxf(acc[r], 0.0f);
        d0 += (double)z * (double)w2r0[r];
        d1 += (double)z * (double)w2r1[r];
      }
#pragma unroll
      for (int off = 32; off > 0; off >>= 1) {
        d0 += __shfl_xor(d0, off, 64);
        d1 += __shfl_xor(d1, off, 64);
      }
      float r0 = (float)(d0 + b20);
      float r1 = (float)(d1 + b21);
      float m = fmaxf(r0, r1);
      float s0 = r0 - m, s1 = r1 - m;
      float lse = logf(expf(s0) + expf(s1));
      float l0 = s0 - lse, l1 = s1 - lse;
      int pidx = ii * 4 + jj;
      float a0 = l0 + gum[2 * pidx];
      float a1 = l1 + gum[2 * pidx + 1];
      int samp = (a1 > a0) ? 1 : 0;
      int tbit = bofs + 24;
      mask = (mask & ~(1ull << tbit)) | ((unsigned long long)samp << tbit);
      if (lane == 0) {
        int pr = si + ii + 4, pc = sj + jj + 4;
        size_t so = ((size_t)(b * 16 + pr) * 16 + pc) * 2;
        out_soft[so] = l0;
        out_soft[so + 1] = l1;
        int po = b * 256 + pr * 16 + pc;
        float fs = (float)samp;
        u_cur[po] = fs;
        v_cur[po] = samp;
        out_u[po] = fs;
        out_v[po] = fs;
      }
    }
  }
}

// ---------------------------------------------------------------------------
// Host-side launch sequence
// ---------------------------------------------------------------------------
extern "C" void kernel_launch(void* const* d_in, const int* in_sizes, int n_in,
                              void* d_out, int out_size, void* d_ws,
                              size_t ws_size, hipStream_t stream) {
  (void)in_sizes; (void)n_in; (void)out_size; (void)ws_size;
  const float* u_in = (const float*)d_in[0];
  const int*   v_in = (const int*)d_in[1];
  const float* emb  = (const float*)d_in[2];
  const float* w1   = (const float*)d_in[3];
  const float* b1   = (const float*)d_in[4];
  const float* w2   = (const float*)d_in[5];
  const float* b2   = (const float*)d_in[6];
  const float* wih  = (const float*)d_in[7];
  const float* whh  = (const float*)d_in[8];
  const float* bih  = (const float*)d_in[9];
  const float* bhh  = (const float*)d_in[10];

  float* ws = (float*)d_ws;
  const size_t HP = (size_t)3 * NB * NC;           // 393216: h parity stride
  float* h0buf = ws;                               // [2][3][NB][NC]
  float* cbuf  = h0buf + 2 * HP;                   // [3][NB][NC]
  float* Hpart = cbuf + (size_t)3 * NB * NC;       // [8][NB][NC]
  float* WDp   = Hpart + (size_t)8 * NB * NC;      // [15][NC]
  float* A0v   = WDp + NFS * NC;                   // [NC]
  float* u_cur = A0v + NC;                         // [NB][16][16]
  int*   v_cur = (int*)(u_cur + NB * NL * NL);     // [NB][16][16]
  unsigned short* Ahi = (unsigned short*)(v_cur + NB * NL * NL); // [2][768][512]
  unsigned short* Alo = Ahi + (size_t)2 * 768 * 512;             // [2][768][512]
  unsigned short* Bhi = Alo + (size_t)2 * 768 * 512;             // [2048][512]
  unsigned short* Blo = Bhi + (size_t)2048 * 512;                // [2048][512]
  const size_t APAR = (size_t)768 * 512;           // parity stride (shorts)

  float* out_soft = (float*)d_out;                 // [NB][16][16][2]
  float* out_u = out_soft + NB * NL * NL * 2;      // [NB][16][16]
  float* out_v = out_u + NB * NL * NL;             // [NB][16][16]

  setup_kernel<<<dim3(4096), dim3(256), 0, stream>>>(
      u_in, v_in, h0buf, cbuf, u_cur, v_cur, out_soft, out_u, out_v,
      (unsigned int*)Ahi);
  split_w_kernel<<<dim3(4096), dim3(256), 0, stream>>>(whh, Bhi, Blo);
  wd_kernel<<<dim3(16), dim3(256), 0, stream>>>(emb, w1, b1, WDp, A0v);

  for (int k = 0; k < 9; k++) {
    if (k > 0) {
      int e = k - 1;
      int col0 = (e % 3 == 0) ? 4 : ((e % 3 == 1) ? 8 : 0);
      int rp = e & 1, wp = rp ^ 1;
      lstm_fused2r_kernel<<<dim3(768), dim3(256), 0, stream>>>(
          Ahi + (size_t)rp * APAR, Alo + (size_t)rp * APAR,
          Ahi + (size_t)wp * APAR, Alo + (size_t)wp * APAR,
          Bhi, Blo, wih, u_cur, bih, bhh, cbuf,
          h0buf + (size_t)wp * HP, col0);
    }
    w1h0_kernel<<<dim3(256), dim3(256), 0, stream>>>(
        h0buf + (size_t)(k & 1) * HP + (size_t)(k / 3) * NB * NC, w1, Hpart);
    pixel_kernel<<<dim3(256), dim3(64), 0, stream>>>(
        WDp, A0v, Hpart, w2, b2, u_cur, v_cur, out_soft, out_u, out_v,
        (k / 3) * 4, (k % 3) * 4, k * 16);
  }
}

// Round 9
// 495.686 us; speedup vs baseline: 1.4309x; 1.0949x over previous
//
#include <hip/hip_runtime.h>
#include <cstdint>
#include <cstddef>

// ---------------------------------------------------------------------------
// Problem constants
// ---------------------------------------------------------------------------
constexpr int NB = 256;   // batch
constexpr int NC = 512;   // c_length
constexpr int NL = 16;    // lattice side
constexpr int NFS = 15;   // neighborhood size

#define PARTITIONABLE 1

// ---------------------------------------------------------------------------
// Threefry2x32-20 (JAX-compatible), usable at compile time and on device
// ---------------------------------------------------------------------------
struct TFOut { uint32_t a, b; };

__host__ __device__ constexpr uint32_t rotl32(uint32_t x, int d) {
  return (x << d) | (x >> (32 - d));
}

__host__ __device__ constexpr TFOut tf2x32(uint32_t k0, uint32_t k1,
                                           uint32_t x0, uint32_t x1) {
  uint32_t k2 = k0 ^ k1 ^ 0x1BD11BDAu;
  x0 += k0; x1 += k1;
  const int R0[4] = {13, 15, 26, 6};
  const int R1[4] = {17, 29, 16, 24};
  for (int i = 0; i < 4; i++) { x0 += x1; x1 = rotl32(x1, R0[i]); x1 ^= x0; }
  x0 += k1; x1 += k2 + 1u;
  for (int i = 0; i < 4; i++) { x0 += x1; x1 = rotl32(x1, R1[i]); x1 ^= x0; }
  x0 += k2; x1 += k0 + 2u;
  for (int i = 0; i < 4; i++) { x0 += x1; x1 = rotl32(x1, R0[i]); x1 ^= x0; }
  x0 += k0; x1 += k1 + 3u;
  for (int i = 0; i < 4; i++) { x0 += x1; x1 = rotl32(x1, R1[i]); x1 ^= x0; }
  x0 += k1; x1 += k2 + 4u;
  for (int i = 0; i < 4; i++) { x0 += x1; x1 = rotl32(x1, R0[i]); x1 ^= x0; }
  x0 += k2; x1 += k0 + 5u;
  return TFOut{x0, x1};
}

struct SubKeys { uint32_t v[288]; };

constexpr SubKeys make_subkeys() {
  SubKeys s{};
  uint32_t k0 = 0u, k1 = 1234u;
  for (int t = 0; t < 144; t++) {
#if PARTITIONABLE
    TFOut nk = tf2x32(k0, k1, 0u, 0u);
    TFOut sk = tf2x32(k0, k1, 0u, 1u);
    s.v[2 * t] = sk.a; s.v[2 * t + 1] = sk.b;
    k0 = nk.a; k1 = nk.b;
#else
    TFOut p0 = tf2x32(k0, k1, 0u, 2u);
    TFOut p1 = tf2x32(k0, k1, 1u, 3u);
    s.v[2 * t] = p0.b; s.v[2 * t + 1] = p1.b;
    k0 = p0.a; k1 = p1.a;
#endif
  }
  return s;
}

__constant__ SubKeys SUBKEYS = make_subkeys();

__device__ __forceinline__ float gumbel_from_bits(uint32_t bits) {
  uint32_t ub = (bits >> 9) | 0x3f800000u;
  float f = __uint_as_float(ub) - 1.0f;
  float u = (f == 0.0f) ? 1.17549435e-38f : f;
  float inner = logf(u);
  float outer = logf(-inner);
  return -outer;
}

// ---------------------------------------------------------------------------
// MFMA / bf16 helpers
// ---------------------------------------------------------------------------
typedef __attribute__((ext_vector_type(8))) short bf16x8;
typedef __attribute__((ext_vector_type(4))) float f32x4;

__device__ __forceinline__ void gl2lds16(const unsigned short* g,
                                         unsigned short* l) {
  // async global -> LDS, 16 B/lane; dst is wave-uniform base + lane*16
  __builtin_amdgcn_global_load_lds(
      (const __attribute__((address_space(1))) unsigned int*)g,
      (__attribute__((address_space(3))) unsigned int*)l, 16, 0, 0);
}

__device__ __forceinline__ uint32_t bf_rne(float x) {
  uint32_t u = __float_as_uint(x);
  return (u + 0x7fffu + ((u >> 16) & 1u)) >> 16;
}

// ---------------------------------------------------------------------------
// Kernel 0: init workspace + outputs
// ---------------------------------------------------------------------------
__global__ __launch_bounds__(256) void setup_kernel(
    const float* __restrict__ u_in, const int* __restrict__ v_in,
    float* __restrict__ h0buf, float* __restrict__ cbuf,
    float* __restrict__ u_cur, int* __restrict__ v_cur,
    float* __restrict__ out_soft, float* __restrict__ out_u,
    float* __restrict__ out_v, unsigned int* __restrict__ az) {
  int idx = blockIdx.x * 256 + threadIdx.x;       // [0, 1048576)
  if (idx < 786432) h0buf[idx] = 0.0f;            // 2 parities x [3][NB][NC]
  if (idx < 3 * NB * NC) cbuf[idx] = 0.0f;        // lstm cell state, 3 sectors
  if (idx < 786432) az[idx] = 0u;                 // Ahi+Alo bf16, 2 parities
  if (idx < NB * NL * NL) {
    float uv = u_in[idx];
    int vv = v_in[idx];
    u_cur[idx] = uv;
    v_cur[idx] = vv;
    out_u[idx] = uv;
    out_v[idx] = (float)vv;
  }
  if (idx < NB * NL * NL * 2) out_soft[idx] = 0.0f;
}

// ---------------------------------------------------------------------------
// Kernel 0b (one-time): split whh into bf16 hi/lo pairs.
// grid = 4096 x 256 (= 2048*512 elements)
// ---------------------------------------------------------------------------
__global__ __launch_bounds__(256) void split_w_kernel(
    const float* __restrict__ whh,
    unsigned short* __restrict__ Bhi, unsigned short* __restrict__ Blo) {
  int idx = blockIdx.x * 256 + threadIdx.x;
  float x = whh[idx];
  uint32_t hb = bf_rne(x);
  float lo = x - __uint_as_float(hb << 16);
  Bhi[idx] = (unsigned short)hb;
  Blo[idx] = (unsigned short)bf_rne(lo);
}

// ---------------------------------------------------------------------------
// Kernel 1: WD[n][c] = W1 · (emb[n,1]-emb[n,0]);  A0 = W1 · Σ emb[n,0] + b1
// ---------------------------------------------------------------------------
__global__ __launch_bounds__(256) void wd_kernel(
    const float* __restrict__ emb, const float* __restrict__ w1,
    const float* __restrict__ b1, float* __restrict__ WD,
    float* __restrict__ A0v) {
  __shared__ double dvec[NC];
  int n = blockIdx.x, tid = threadIdx.x;
  for (int k = tid; k < NC; k += 256) {
    if (n < NFS) {
      dvec[k] = (double)emb[(n * 2 + 1) * NC + k] - (double)emb[(n * 2) * NC + k];
    } else {
      double s = 0.0;
      for (int nn = 0; nn < NFS; nn++) s += (double)emb[(nn * 2) * NC + k];
      dvec[k] = s;
    }
  }
  __syncthreads();
  for (int c = tid; c < NC; c += 256) {
    double acc = 0.0;
    const float* wrow = w1 + (size_t)c * NC;
    for (int k = 0; k < NC; k++) acc += dvec[k] * (double)wrow[k];
    if (n < NFS) WD[n * NC + c] = (float)acc;
    else         A0v[c] = (float)(acc + (double)b1[c]);
  }
}

// ---------------------------------------------------------------------------
// Kernel 2: fused LSTM step (r5-best structure) + bijective XCD swizzle.
// grid = 24(rt: 32-row tiles) x 32(ct: 16-c tiles) = 768 blocks, 256 thr
// = 4 waves = 3 blocks/CU even (LDS 50 KB/block).
// XCD swizzle (T1, m204): bx = (bid&7)*96 + bid>>3 — each XCD gets a
// contiguous chunk of 96 tiles = 3 rt-groups x all ct, so its A slice
// (192 KB) and full B (4 MB) are L2-resident; the 32x A re-read and 3x
// per-XCD B re-read become L2 hits (was ~147 MB of L2-miss traffic).
// Each wave: K-slice of 128 (4 chunks BK=32), wave-tile 32 rows x 64 gcols
// (gate-complete), acc 2x4 frags. Partials reduced via padded LDS; epilogue
// adds bias + exact-fp32 uv·wih term + LSTM nonlinearity; writes h (fp32),
// bf16 hi/lo split, cbuf.  Numerics identical to r5 (pure index permute).
// ---------------------------------------------------------------------------
__global__ __launch_bounds__(256) void lstm_fused2_kernel(
    const unsigned short* __restrict__ Ah_r, const unsigned short* __restrict__ Al_r,
    unsigned short* __restrict__ Ah_w, unsigned short* __restrict__ Al_w,
    const unsigned short* __restrict__ Bhi, const unsigned short* __restrict__ Blo,
    const float* __restrict__ wih, const float* __restrict__ u_cur,
    const float* __restrict__ bih, const float* __restrict__ bhh,
    float* __restrict__ cbuf, float* __restrict__ h_out, int col0) {
  // 48 KB staging: sA[4][32*32] | sAl | sB[4][64*32] | sBl  (bf16)
  __shared__ __align__(16) unsigned short SM[24576];
  __shared__ float uvs[32][16];

  unsigned short* sA  = SM;            // 4096 shorts
  unsigned short* sAl = SM + 4096;     // 4096
  unsigned short* sB  = SM + 8192;     // 8192
  unsigned short* sBl = SM + 16384;    // 8192

  int bx0 = blockIdx.x;
  int bx = (bx0 & 7) * 96 + (bx0 >> 3);  // bijective XCD swizzle (768 % 8 == 0)
  int rt = bx >> 5;                    // [0,24)
  int ct = bx & 31;                    // [0,32)
  int tid = threadIdx.x;
  int w = tid >> 6, lane = tid & 63;
  int l15 = lane & 15, kg = lane >> 4;
  int sw = (l15 >> 1) & 3;             // read-side swizzle
  int grow0 = rt * 32;                 // global row base (sector*256 + batch)
  int s = rt >> 3;                     // sector index
  int b0 = (rt & 7) * 32;              // batch base

  // stage uv (exact fp32) for the epilogue's uv·wih term
  {
    int idx = tid;
    for (int t = 0; t < 2; t++, idx += 256) {
      int r = idx >> 4, nn = idx & 15;
      uvs[r][nn] =
          u_cur[(b0 + r) * 256 + (s * 4 + (nn >> 2)) * 16 + col0 + (nn & 3)];
    }
  }

  f32x4 acc[2][4];
#pragma unroll
  for (int i = 0; i < 2; i++)
#pragma unroll
    for (int j = 0; j < 4; j++) acc[i][j] = (f32x4){0.f, 0.f, 0.f, 0.f};

  // ---- main K loop: each wave covers k in [w*128, w*128+128), 4 chunks ----
  for (int kc = 0; kc < 4; kc++) {
    int k0 = w * 128 + kc * 32;
    if (kc > 0) __syncthreads();       // prior frag reads done before restage
    // stage A hi/lo: 32 rows x 32 k each -> 2 gl2lds per array
#pragma unroll
    for (int q = 0; q < 2; q++) {
      int slot = q * 64 + lane;        // [0,128)
      int r = slot >> 2;
      int c2 = (slot & 3) ^ ((r >> 1) & 3);
      size_t so = (size_t)(grow0 + r) * 512 + k0 + c2 * 8;
      gl2lds16(Ah_r + so, sA + w * 1024 + q * 512);
      gl2lds16(Al_r + so, sAl + w * 1024 + q * 512);
    }
    // stage B hi/lo: 64 gcols x 32 k each -> 4 gl2lds per array
#pragma unroll
    for (int q = 0; q < 4; q++) {
      int slot = q * 64 + lane;        // [0,256)
      int r = slot >> 2;
      int c2 = (slot & 3) ^ ((r >> 1) & 3);
      int nidx = (r >> 4) * 512 + ct * 16 + (r & 15);  // gate*512 + c
      size_t so = (size_t)nidx * 512 + k0 + c2 * 8;
      gl2lds16(Bhi + so, sB + w * 2048 + q * 512);
      gl2lds16(Blo + so, sBl + w * 2048 + q * 512);
    }
    __syncthreads();                   // drains vmcnt -> LDS data visible

    bf16x8 ah[2], al[2];
#pragma unroll
    for (int i = 0; i < 2; i++) {
      int ro = w * 1024 + (i * 16 + l15) * 32 + ((kg ^ sw) * 8);
      ah[i] = *(const bf16x8*)&sA[ro];
      al[i] = *(const bf16x8*)&sAl[ro];
    }
#pragma unroll
    for (int j = 0; j < 4; j++) {
      int ro = w * 2048 + (j * 16 + l15) * 32 + ((kg ^ sw) * 8);
      bf16x8 bh = *(const bf16x8*)&sB[ro];
      bf16x8 bl = *(const bf16x8*)&sBl[ro];
#pragma unroll
      for (int i = 0; i < 2; i++) {
        acc[i][j] = __builtin_amdgcn_mfma_f32_16x16x32_bf16(ah[i], bh,
                                                            acc[i][j], 0, 0, 0);
        acc[i][j] = __builtin_amdgcn_mfma_f32_16x16x32_bf16(ah[i], bl,
                                                            acc[i][j], 0, 0, 0);
        acc[i][j] = __builtin_amdgcn_mfma_f32_16x16x32_bf16(al[i], bh,
                                                            acc[i][j], 0, 0, 0);
      }
    }
  }

  // ---- cross-wave reduction through LDS (padded, conflict-free) ----
  float* red = (float*)SM;             // [512][17] f32 = 34 KB (fits 48)
  __syncthreads();                     // all frag reads done; safe to overwrite
#pragma unroll
  for (int i = 0; i < 2; i++)
#pragma unroll
    for (int g = 0; g < 4; g++)
#pragma unroll
      for (int rr = 0; rr < 4; rr++) {
        int row = i * 16 + kg * 4 + rr;    // m89 C/D layout
        red[((w * 4 + g) * 32 + row) * 17 + l15] = acc[i][g][rr];
      }
  __syncthreads();

  // ---- epilogue: 2 rows per thread covers the full 32x16 tile ----
  int rbase = tid >> 4, c = tid & 15;      // rbase in [0,16)
  int cglob = ct * 16 + c;
  float bi_[4], bh_[4];
#pragma unroll
  for (int g = 0; g < 4; g++) {
    bi_[g] = bih[g * 512 + cglob];
    bh_[g] = bhh[g * 512 + cglob];
  }
#pragma unroll
  for (int rh = 0; rh < 2; rh++) {
    int row = rh * 16 + rbase;               // [0,32)
    int grow = grow0 + row;
    float uvr[16];
#pragma unroll
    for (int nn = 0; nn < 16; nn++) uvr[nn] = uvs[row][nn];
    float gv[4];
#pragma unroll
    for (int g = 0; g < 4; g++) {
      float v = 0.0f;
#pragma unroll
      for (int ww = 0; ww < 4; ww++)
        v += red[((ww * 4 + g) * 32 + row) * 17 + c];
      const float* wr = wih + (size_t)(g * 512 + cglob) * 16;
#pragma unroll
      for (int nn = 0; nn < 16; nn++) v = fmaf(uvr[nn], wr[nn], v);
      gv[g] = v + bi_[g] + bh_[g];
    }
    size_t off = (size_t)grow * NC + cglob;
    float c_old = cbuf[off];
    float sig_i = 1.0f / (1.0f + expf(-gv[0]));
    float sig_f = 1.0f / (1.0f + expf(-gv[1]));
    float tg    = tanhf(gv[2]);
    float sig_o = 1.0f / (1.0f + expf(-gv[3]));
    float cn = sig_f * c_old + sig_i * tg;
    float hn = sig_o * tanhf(cn);
    cbuf[off] = cn;
    h_out[off] = hn;
    uint32_t hb = bf_rne(hn);
    float lo = hn - __uint_as_float(hb << 16);
    Ah_w[off] = (unsigned short)hb;
    Al_w[off] = (unsigned short)bf_rne(lo);
  }
}

// ---------------------------------------------------------------------------
// Kernel 3: Hpart[ks][b][c] partials of H = W1 · h0 (fp32 — kept exact).
// grid = 8(ks,K=64 each) * 4(bt) * 8(ct) = 256 blocks, 256 threads.
// ---------------------------------------------------------------------------
__global__ __launch_bounds__(256) void w1h0_kernel(
    const float* __restrict__ h_in,   // [NB][NC] slice for (parity, s=i)
    const float* __restrict__ w1, float* __restrict__ Hpart) {
  int bx = blockIdx.x;
  int ks = bx >> 5;
  int bt = (bx >> 3) & 3;
  int ct = bx & 7;
  int tid = threadIdx.x, tn = tid & 15, tb = tid >> 4;

  __shared__ float hs[64][36];
  __shared__ float wt[64][36];
  float acc[4][4] = {};
  const float* hbase = h_in + (size_t)(bt * 64) * NC;

  for (int kc = 0; kc < 2; kc++) {
    int k0 = ks * 64 + kc * 32;
    __syncthreads();
    for (int t = 0; t < 2; t++) {
      int idx = tid + t * 256;
      int row = idx >> 3, kk4 = idx & 7;
      *(float4*)&hs[row][kk4 * 4] =
          *(const float4*)(hbase + (size_t)row * NC + k0 + kk4 * 4);
      int wrow = ct * 64 + row;
      *(float4*)&wt[row][kk4 * 4] =
          *(const float4*)(w1 + (size_t)wrow * NC + k0 + kk4 * 4);
    }
    __syncthreads();
#pragma unroll
    for (int kk4 = 0; kk4 < 8; kk4++) {
      float4 hv[4], wv[4];
#pragma unroll
      for (int i = 0; i < 4; i++) hv[i] = *(float4*)&hs[tb * 4 + i][kk4 * 4];
#pragma unroll
      for (int j = 0; j < 4; j++) wv[j] = *(float4*)&wt[tn + 16 * j][kk4 * 4];
#pragma unroll
      for (int i = 0; i < 4; i++)
#pragma unroll
        for (int j = 0; j < 4; j++)
          acc[i][j] += hv[i].x * wv[j].x + hv[i].y * wv[j].y +
                       hv[i].z * wv[j].z + hv[i].w * wv[j].w;
    }
  }
#pragma unroll
  for (int i = 0; i < 4; i++) {
    int b = bt * 64 + tb * 4 + i;
#pragma unroll
    for (int j = 0; j < 4; j++) {
      int cidx = ct * 64 + tn + 16 * j;
      Hpart[((size_t)ks * NB + b) * NC + cidx] = acc[i][j];
    }
  }
}

// ---------------------------------------------------------------------------
// Kernel 4: 16-pixel autoregressive block (register version, 8-partial sum).
// ---------------------------------------------------------------------------
__global__ __launch_bounds__(64) void pixel_kernel(
    const float* __restrict__ WD, const float* __restrict__ A0v,
    const float* __restrict__ Hpart, const float* __restrict__ w2,
    const float* __restrict__ b2, float* __restrict__ u_cur,
    int* __restrict__ v_cur, float* __restrict__ out_soft,
    float* __restrict__ out_u, float* __restrict__ out_v,
    int si, int sj, int t_base) {
  int b = blockIdx.x, lane = threadIdx.x;
  __shared__ float gum[32];

  int widx = (lane < 49) ? lane : 48;
  int vv = v_cur[b * 256 + (si + 1 + widx / 7) * 16 + (sj + 1 + widx % 7)];
  unsigned long long mask = __ballot((lane < 49) && (vv != 0));

  if (lane < 32) {
    int t = t_base + (lane >> 1);
    uint32_t sk0 = SUBKEYS.v[2 * t], sk1 = SUBKEYS.v[2 * t + 1];
    uint32_t bits;
#if PARTITIONABLE
    TFOut o = tf2x32(sk0, sk1, 0u, (uint32_t)(2 * b + (lane & 1)));
    bits = o.a ^ o.b;
#else
    uint32_t f = (uint32_t)(2 * b + (lane & 1));
    if (f < 256u) { TFOut o = tf2x32(sk0, sk1, f, f + 256u); bits = o.a; }
    else          { TFOut o = tf2x32(sk0, sk1, f - 256u, f); bits = o.b; }
#endif
    gum[lane] = gumbel_from_bits(bits);
  }

  float wdreg[NFS][8];
#pragma unroll
  for (int n = 0; n < NFS; n++)
#pragma unroll
    for (int r = 0; r < 8; r++) wdreg[n][r] = WD[n * NC + lane + 64 * r];

  float w2r0[8], w2r1[8];
#pragma unroll
  for (int r = 0; r < 8; r++) {
    w2r0[r] = w2[lane + 64 * r];
    w2r1[r] = w2[NC + lane + 64 * r];
  }
  double b20 = (double)b2[0], b21 = (double)b2[1];

  float base[8];
#pragma unroll
  for (int r = 0; r < 8; r++) {
    int c = lane + 64 * r;
    float v = A0v[c];
#pragma unroll
    for (int ks = 0; ks < 8; ks++) v += Hpart[((size_t)ks * NB + b) * NC + c];
    base[r] = v;
  }
  __syncthreads();

#pragma unroll 1
  for (int ii = 0; ii < 4; ii++) {
#pragma unroll 1
    for (int jj = 0; jj < 4; jj++) {
      int bofs = ii * 7 + jj;
      float acc[8];
#pragma unroll
      for (int r = 0; r < 8; r++) acc[r] = base[r];
#pragma unroll
      for (int n = 0; n < NFS; n++) {
        const int OFF = (n / 4) * 7 + (n % 4);
        float pf = (float)((unsigned)((mask >> (bofs + OFF)) & 1ull));
#pragma unroll
        for (int r = 0; r < 8; r++) acc[r] = fmaf(pf, wdreg[n][r], acc[r]);
      }
      double d0 = 0.0, d1 = 0.0;
#pragma unroll
      for (int r = 0; r < 8; r++) {
        float z = fmaxf(acc[r], 0.0f);
        d0 += (double)z * (double)w2r0[r];
        d1 += (double)z * (double)w2r1[r];
      }
#pragma unroll
      for (int off = 32; off > 0; off >>= 1) {
        d0 += __shfl_xor(d0, off, 64);
        d1 += __shfl_xor(d1, off, 64);
      }
      float r0 = (float)(d0 + b20);
      float r1 = (float)(d1 + b21);
      float m = fmaxf(r0, r1);
      float s0 = r0 - m, s1 = r1 - m;
      float lse = logf(expf(s0) + expf(s1));
      float l0 = s0 - lse, l1 = s1 - lse;
      int pidx = ii * 4 + jj;
      float a0 = l0 + gum[2 * pidx];
      float a1 = l1 + gum[2 * pidx + 1];
      int samp = (a1 > a0) ? 1 : 0;
      int tbit = bofs + 24;
      mask = (mask & ~(1ull << tbit)) | ((unsigned long long)samp << tbit);
      if (lane == 0) {
        int pr = si + ii + 4, pc = sj + jj + 4;
        size_t so = ((size_t)(b * 16 + pr) * 16 + pc) * 2;
        out_soft[so] = l0;
        out_soft[so + 1] = l1;
        int po = b * 256 + pr * 16 + pc;
        float fs = (float)samp;
        u_cur[po] = fs;
        v_cur[po] = samp;
        out_u[po] = fs;
        out_v[po] = fs;
      }
    }
  }
}

// ---------------------------------------------------------------------------
// Host-side launch sequence
// ---------------------------------------------------------------------------
extern "C" void kernel_launch(void* const* d_in, const int* in_sizes, int n_in,
                              void* d_out, int out_size, void* d_ws,
                              size_t ws_size, hipStream_t stream) {
  (void)in_sizes; (void)n_in; (void)out_size; (void)ws_size;
  const float* u_in = (const float*)d_in[0];
  const int*   v_in = (const int*)d_in[1];
  const float* emb  = (const float*)d_in[2];
  const float* w1   = (const float*)d_in[3];
  const float* b1   = (const float*)d_in[4];
  const float* w2   = (const float*)d_in[5];
  const float* b2   = (const float*)d_in[6];
  const float* wih  = (const float*)d_in[7];
  const float* whh  = (const float*)d_in[8];
  const float* bih  = (const float*)d_in[9];
  const float* bhh  = (const float*)d_in[10];

  float* ws = (float*)d_ws;
  const size_t HP = (size_t)3 * NB * NC;           // 393216: h parity stride
  float* h0buf = ws;                               // [2][3][NB][NC]
  float* cbuf  = h0buf + 2 * HP;                   // [3][NB][NC]
  float* Hpart = cbuf + (size_t)3 * NB * NC;       // [8][NB][NC]
  float* WDp   = Hpart + (size_t)8 * NB * NC;      // [15][NC]
  float* A0v   = WDp + NFS * NC;                   // [NC]
  float* u_cur = A0v + NC;                         // [NB][16][16]
  int*   v_cur = (int*)(u_cur + NB * NL * NL);     // [NB][16][16]
  unsigned short* Ahi = (unsigned short*)(v_cur + NB * NL * NL); // [2][768][512]
  unsigned short* Alo = Ahi + (size_t)2 * 768 * 512;             // [2][768][512]
  unsigned short* Bhi = Alo + (size_t)2 * 768 * 512;             // [2048][512]
  unsigned short* Blo = Bhi + (size_t)2048 * 512;                // [2048][512]
  const size_t APAR = (size_t)768 * 512;           // parity stride (shorts)

  float* out_soft = (float*)d_out;                 // [NB][16][16][2]
  float* out_u = out_soft + NB * NL * NL * 2;      // [NB][16][16]
  float* out_v = out_u + NB * NL * NL;             // [NB][16][16]

  setup_kernel<<<dim3(4096), dim3(256), 0, stream>>>(
      u_in, v_in, h0buf, cbuf, u_cur, v_cur, out_soft, out_u, out_v,
      (unsigned int*)Ahi);
  split_w_kernel<<<dim3(4096), dim3(256), 0, stream>>>(whh, Bhi, Blo);
  wd_kernel<<<dim3(16), dim3(256), 0, stream>>>(emb, w1, b1, WDp, A0v);

  for (int k = 0; k < 9; k++) {
    if (k > 0) {
      int e = k - 1;
      int col0 = (e % 3 == 0) ? 4 : ((e % 3 == 1) ? 8 : 0);
      int rp = e & 1, wp = rp ^ 1;
      lstm_fused2_kernel<<<dim3(768), dim3(256), 0, stream>>>(
          Ahi + (size_t)rp * APAR, Alo + (size_t)rp * APAR,
          Ahi + (size_t)wp * APAR, Alo + (size_t)wp * APAR,
          Bhi, Blo, wih, u_cur, bih, bhh, cbuf,
          h0buf + (size_t)wp * HP, col0);
    }
    w1h0_kernel<<<dim3(256), dim3(256), 0, stream>>>(
        h0buf + (size_t)(k & 1) * HP + (size_t)(k / 3) * NB * NC, w1, Hpart);
    pixel_kernel<<<dim3(256), dim3(64), 0, stream>>>(
        WDp, A0v, Hpart, w2, b2, u_cur, v_cur, out_soft, out_u, out_v,
        (k / 3) * 4, (k % 3) * 4, k * 16);
  }
}

// Round 10
// 484.350 us; speedup vs baseline: 1.4644x; 1.0234x over previous
//
#include <hip/hip_runtime.h>
#include <cstdint>
#include <cstddef>

// ---------------------------------------------------------------------------
// Problem constants
// ---------------------------------------------------------------------------
constexpr int NB = 256;   // batch
constexpr int NC = 512;   // c_length
constexpr int NL = 16;    // lattice side
constexpr int NFS = 15;   // neighborhood size

#define PARTITIONABLE 1

// ---------------------------------------------------------------------------
// Threefry2x32-20 (JAX-compatible), usable at compile time and on device
// ---------------------------------------------------------------------------
struct TFOut { uint32_t a, b; };

__host__ __device__ constexpr uint32_t rotl32(uint32_t x, int d) {
  return (x << d) | (x >> (32 - d));
}

__host__ __device__ constexpr TFOut tf2x32(uint32_t k0, uint32_t k1,
                                           uint32_t x0, uint32_t x1) {
  uint32_t k2 = k0 ^ k1 ^ 0x1BD11BDAu;
  x0 += k0; x1 += k1;
  const int R0[4] = {13, 15, 26, 6};
  const int R1[4] = {17, 29, 16, 24};
  for (int i = 0; i < 4; i++) { x0 += x1; x1 = rotl32(x1, R0[i]); x1 ^= x0; }
  x0 += k1; x1 += k2 + 1u;
  for (int i = 0; i < 4; i++) { x0 += x1; x1 = rotl32(x1, R1[i]); x1 ^= x0; }
  x0 += k2; x1 += k0 + 2u;
  for (int i = 0; i < 4; i++) { x0 += x1; x1 = rotl32(x1, R0[i]); x1 ^= x0; }
  x0 += k0; x1 += k1 + 3u;
  for (int i = 0; i < 4; i++) { x0 += x1; x1 = rotl32(x1, R1[i]); x1 ^= x0; }
  x0 += k1; x1 += k2 + 4u;
  for (int i = 0; i < 4; i++) { x0 += x1; x1 = rotl32(x1, R0[i]); x1 ^= x0; }
  x0 += k2; x1 += k0 + 5u;
  return TFOut{x0, x1};
}

struct SubKeys { uint32_t v[288]; };

constexpr SubKeys make_subkeys() {
  SubKeys s{};
  uint32_t k0 = 0u, k1 = 1234u;
  for (int t = 0; t < 144; t++) {
#if PARTITIONABLE
    TFOut nk = tf2x32(k0, k1, 0u, 0u);
    TFOut sk = tf2x32(k0, k1, 0u, 1u);
    s.v[2 * t] = sk.a; s.v[2 * t + 1] = sk.b;
    k0 = nk.a; k1 = nk.b;
#else
    TFOut p0 = tf2x32(k0, k1, 0u, 2u);
    TFOut p1 = tf2x32(k0, k1, 1u, 3u);
    s.v[2 * t] = p0.b; s.v[2 * t + 1] = p1.b;
    k0 = p0.a; k1 = p1.a;
#endif
  }
  return s;
}

__constant__ SubKeys SUBKEYS = make_subkeys();

__device__ __forceinline__ float gumbel_from_bits(uint32_t bits) {
  uint32_t ub = (bits >> 9) | 0x3f800000u;
  float f = __uint_as_float(ub) - 1.0f;
  float u = (f == 0.0f) ? 1.17549435e-38f : f;
  float inner = logf(u);
  float outer = logf(-inner);
  return -outer;
}

// ---------------------------------------------------------------------------
// MFMA / bf16 helpers
// ---------------------------------------------------------------------------
typedef __attribute__((ext_vector_type(8))) short bf16x8;
typedef __attribute__((ext_vector_type(4))) float f32x4;

__device__ __forceinline__ void gl2lds16(const unsigned short* g,
                                         unsigned short* l) {
  // async global -> LDS, 16 B/lane; dst is wave-uniform base + lane*16
  __builtin_amdgcn_global_load_lds(
      (const __attribute__((address_space(1))) unsigned int*)g,
      (__attribute__((address_space(3))) unsigned int*)l, 16, 0, 0);
}

__device__ __forceinline__ uint32_t bf_rne(float x) {
  uint32_t u = __float_as_uint(x);
  return (u + 0x7fffu + ((u >> 16) & 1u)) >> 16;
}

// ---------------------------------------------------------------------------
// Kernel 0: init workspace + outputs
// ---------------------------------------------------------------------------
__global__ __launch_bounds__(256) void setup_kernel(
    const float* __restrict__ u_in, const int* __restrict__ v_in,
    float* __restrict__ h0buf, float* __restrict__ cbuf,
    float* __restrict__ u_cur, int* __restrict__ v_cur,
    float* __restrict__ out_soft, float* __restrict__ out_u,
    float* __restrict__ out_v, unsigned int* __restrict__ az) {
  int idx = blockIdx.x * 256 + threadIdx.x;       // [0, 1048576)
  if (idx < 786432) h0buf[idx] = 0.0f;            // 2 parities x [3][NB][NC]
  if (idx < 3 * NB * NC) cbuf[idx] = 0.0f;        // lstm cell state, 3 sectors
  if (idx < 786432) az[idx] = 0u;                 // Ahi+Alo bf16, 2 parities
  if (idx < NB * NL * NL) {
    float uv = u_in[idx];
    int vv = v_in[idx];
    u_cur[idx] = uv;
    v_cur[idx] = vv;
    out_u[idx] = uv;
    out_v[idx] = (float)vv;
  }
  if (idx < NB * NL * NL * 2) out_soft[idx] = 0.0f;
}

// ---------------------------------------------------------------------------
// Kernel 0b (one-time): split whh into bf16 hi/lo pairs.
// grid = 4096 x 256 (= 2048*512 elements)
// ---------------------------------------------------------------------------
__global__ __launch_bounds__(256) void split_w_kernel(
    const float* __restrict__ whh,
    unsigned short* __restrict__ Bhi, unsigned short* __restrict__ Blo) {
  int idx = blockIdx.x * 256 + threadIdx.x;
  float x = whh[idx];
  uint32_t hb = bf_rne(x);
  float lo = x - __uint_as_float(hb << 16);
  Bhi[idx] = (unsigned short)hb;
  Blo[idx] = (unsigned short)bf_rne(lo);
}

// ---------------------------------------------------------------------------
// Kernel 1: WD[n][c] = W1 · (emb[n,1]-emb[n,0]);  A0 = W1 · Σ emb[n,0] + b1
// ---------------------------------------------------------------------------
__global__ __launch_bounds__(256) void wd_kernel(
    const float* __restrict__ emb, const float* __restrict__ w1,
    const float* __restrict__ b1, float* __restrict__ WD,
    float* __restrict__ A0v) {
  __shared__ double dvec[NC];
  int n = blockIdx.x, tid = threadIdx.x;
  for (int k = tid; k < NC; k += 256) {
    if (n < NFS) {
      dvec[k] = (double)emb[(n * 2 + 1) * NC + k] - (double)emb[(n * 2) * NC + k];
    } else {
      double s = 0.0;
      for (int nn = 0; nn < NFS; nn++) s += (double)emb[(nn * 2) * NC + k];
      dvec[k] = s;
    }
  }
  __syncthreads();
  for (int c = tid; c < NC; c += 256) {
    double acc = 0.0;
    const float* wrow = w1 + (size_t)c * NC;
    for (int k = 0; k < NC; k++) acc += dvec[k] * (double)wrow[k];
    if (n < NFS) WD[n * NC + c] = (float)acc;
    else         A0v[c] = (float)(acc + (double)b1[c]);
  }
}

// ---------------------------------------------------------------------------
// Kernel 2: fused LSTM step (r5-best structure) + ct-partitioned XCD map.
// grid = 24(rt: 32-row tiles) x 32(ct: 16-c tiles) = 768 blocks, 256 thr
// = 4 waves = 3 blocks/CU even (LDS 50 KB/block) — ALL blocks co-resident.
// XCD partition (r10 fix of r9): each XCD owns 4 ct-groups x ALL 24 rt:
//   xcd = bid&7; i = bid>>3; ct = xcd*4 + (i&3); rt = i>>2   (bijective)
// Per-XCD working set = full A (1.5 MB) + its B slice (0.5 MB) + h/cbuf
// slices ~= 2.5 MB < 4 MB L2  ->  B's 24x and A's 4x re-reads become L2
// hits.  (r9's rt-partition left full B per XCD: 4.2 MB > L2 -> thrash,
// which is why it was null.)  Numerics identical to r5 (index permute).
// Each wave: K-slice of 128 (4 chunks BK=32), wave-tile 32 rows x 64 gcols
// (gate-complete), acc 2x4 frags. Partials reduced via padded LDS; epilogue
// adds bias + exact-fp32 uv·wih term + LSTM nonlinearity; writes h (fp32),
// bf16 hi/lo split, cbuf.
// ---------------------------------------------------------------------------
__global__ __launch_bounds__(256) void lstm_fused2_kernel(
    const unsigned short* __restrict__ Ah_r, const unsigned short* __restrict__ Al_r,
    unsigned short* __restrict__ Ah_w, unsigned short* __restrict__ Al_w,
    const unsigned short* __restrict__ Bhi, const unsigned short* __restrict__ Blo,
    const float* __restrict__ wih, const float* __restrict__ u_cur,
    const float* __restrict__ bih, const float* __restrict__ bhh,
    float* __restrict__ cbuf, float* __restrict__ h_out, int col0) {
  // 48 KB staging: sA[4][32*32] | sAl | sB[4][64*32] | sBl  (bf16)
  __shared__ __align__(16) unsigned short SM[24576];
  __shared__ float uvs[32][16];

  unsigned short* sA  = SM;            // 4096 shorts
  unsigned short* sAl = SM + 4096;     // 4096
  unsigned short* sB  = SM + 8192;     // 8192
  unsigned short* sBl = SM + 16384;    // 8192

  int bx0 = blockIdx.x;
  int xcd = bx0 & 7;
  int i5 = bx0 >> 3;                   // [0,96)
  int ct = xcd * 4 + (i5 & 3);         // [0,32): 4 ct-groups per XCD
  int rt = i5 >> 2;                    // [0,24): all rt on every XCD
  int tid = threadIdx.x;
  int w = tid >> 6, lane = tid & 63;
  int l15 = lane & 15, kg = lane >> 4;
  int sw = (l15 >> 1) & 3;             // read-side swizzle
  int grow0 = rt * 32;                 // global row base (sector*256 + batch)
  int s = rt >> 3;                     // sector index
  int b0 = (rt & 7) * 32;              // batch base

  // stage uv (exact fp32) for the epilogue's uv·wih term
  {
    int idx = tid;
    for (int t = 0; t < 2; t++, idx += 256) {
      int r = idx >> 4, nn = idx & 15;
      uvs[r][nn] =
          u_cur[(b0 + r) * 256 + (s * 4 + (nn >> 2)) * 16 + col0 + (nn & 3)];
    }
  }

  f32x4 acc[2][4];
#pragma unroll
  for (int i = 0; i < 2; i++)
#pragma unroll
    for (int j = 0; j < 4; j++) acc[i][j] = (f32x4){0.f, 0.f, 0.f, 0.f};

  // ---- main K loop: each wave covers k in [w*128, w*128+128), 4 chunks ----
  for (int kc = 0; kc < 4; kc++) {
    int k0 = w * 128 + kc * 32;
    if (kc > 0) __syncthreads();       // prior frag reads done before restage
    // stage A hi/lo: 32 rows x 32 k each -> 2 gl2lds per array
#pragma unroll
    for (int q = 0; q < 2; q++) {
      int slot = q * 64 + lane;        // [0,128)
      int r = slot >> 2;
      int c2 = (slot & 3) ^ ((r >> 1) & 3);
      size_t so = (size_t)(grow0 + r) * 512 + k0 + c2 * 8;
      gl2lds16(Ah_r + so, sA + w * 1024 + q * 512);
      gl2lds16(Al_r + so, sAl + w * 1024 + q * 512);
    }
    // stage B hi/lo: 64 gcols x 32 k each -> 4 gl2lds per array
#pragma unroll
    for (int q = 0; q < 4; q++) {
      int slot = q * 64 + lane;        // [0,256)
      int r = slot >> 2;
      int c2 = (slot & 3) ^ ((r >> 1) & 3);
      int nidx = (r >> 4) * 512 + ct * 16 + (r & 15);  // gate*512 + c
      size_t so = (size_t)nidx * 512 + k0 + c2 * 8;
      gl2lds16(Bhi + so, sB + w * 2048 + q * 512);
      gl2lds16(Blo + so, sBl + w * 2048 + q * 512);
    }
    __syncthreads();                   // drains vmcnt -> LDS data visible

    bf16x8 ah[2], al[2];
#pragma unroll
    for (int i = 0; i < 2; i++) {
      int ro = w * 1024 + (i * 16 + l15) * 32 + ((kg ^ sw) * 8);
      ah[i] = *(const bf16x8*)&sA[ro];
      al[i] = *(const bf16x8*)&sAl[ro];
    }
#pragma unroll
    for (int j = 0; j < 4; j++) {
      int ro = w * 2048 + (j * 16 + l15) * 32 + ((kg ^ sw) * 8);
      bf16x8 bh = *(const bf16x8*)&sB[ro];
      bf16x8 bl = *(const bf16x8*)&sBl[ro];
#pragma unroll
      for (int i = 0; i < 2; i++) {
        acc[i][j] = __builtin_amdgcn_mfma_f32_16x16x32_bf16(ah[i], bh,
                                                            acc[i][j], 0, 0, 0);
        acc[i][j] = __builtin_amdgcn_mfma_f32_16x16x32_bf16(ah[i], bl,
                                                            acc[i][j], 0, 0, 0);
        acc[i][j] = __builtin_amdgcn_mfma_f32_16x16x32_bf16(al[i], bh,
                                                            acc[i][j], 0, 0, 0);
      }
    }
  }

  // ---- cross-wave reduction through LDS (padded, conflict-free) ----
  float* red = (float*)SM;             // [512][17] f32 = 34 KB (fits 48)
  __syncthreads();                     // all frag reads done; safe to overwrite
#pragma unroll
  for (int i = 0; i < 2; i++)
#pragma unroll
    for (int g = 0; g < 4; g++)
#pragma unroll
      for (int rr = 0; rr < 4; rr++) {
        int row = i * 16 + kg * 4 + rr;    // m89 C/D layout
        red[((w * 4 + g) * 32 + row) * 17 + l15] = acc[i][g][rr];
      }
  __syncthreads();

  // ---- epilogue: 2 rows per thread covers the full 32x16 tile ----
  int rbase = tid >> 4, c = tid & 15;      // rbase in [0,16)
  int cglob = ct * 16 + c;
  float bi_[4], bh_[4];
#pragma unroll
  for (int g = 0; g < 4; g++) {
    bi_[g] = bih[g * 512 + cglob];
    bh_[g] = bhh[g * 512 + cglob];
  }
#pragma unroll
  for (int rh = 0; rh < 2; rh++) {
    int row = rh * 16 + rbase;               // [0,32)
    int grow = grow0 + row;
    float uvr[16];
#pragma unroll
    for (int nn = 0; nn < 16; nn++) uvr[nn] = uvs[row][nn];
    float gv[4];
#pragma unroll
    for (int g = 0; g < 4; g++) {
      float v = 0.0f;
#pragma unroll
      for (int ww = 0; ww < 4; ww++)
        v += red[((ww * 4 + g) * 32 + row) * 17 + c];
      const float* wr = wih + (size_t)(g * 512 + cglob) * 16;
#pragma unroll
      for (int nn = 0; nn < 16; nn++) v = fmaf(uvr[nn], wr[nn], v);
      gv[g] = v + bi_[g] + bh_[g];
    }
    size_t off = (size_t)grow * NC + cglob;
    float c_old = cbuf[off];
    float sig_i = 1.0f / (1.0f + expf(-gv[0]));
    float sig_f = 1.0f / (1.0f + expf(-gv[1]));
    float tg    = tanhf(gv[2]);
    float sig_o = 1.0f / (1.0f + expf(-gv[3]));
    float cn = sig_f * c_old + sig_i * tg;
    float hn = sig_o * tanhf(cn);
    cbuf[off] = cn;
    h_out[off] = hn;
    uint32_t hb = bf_rne(hn);
    float lo = hn - __uint_as_float(hb << 16);
    Ah_w[off] = (unsigned short)hb;
    Al_w[off] = (unsigned short)bf_rne(lo);
  }
}

// ---------------------------------------------------------------------------
// Kernel 3: Hpart[ks][b][c] partials of H = W1 · h0 (fp32 — kept exact).
// grid = 8(ks,K=64 each) * 4(bt) * 8(ct) = 256 blocks, 256 threads.
// ---------------------------------------------------------------------------
__global__ __launch_bounds__(256) void w1h0_kernel(
    const float* __restrict__ h_in,   // [NB][NC] slice for (parity, s=i)
    const float* __restrict__ w1, float* __restrict__ Hpart) {
  int bx = blockIdx.x;
  int ks = bx >> 5;
  int bt = (bx >> 3) & 3;
  int ct = bx & 7;
  int tid = threadIdx.x, tn = tid & 15, tb = tid >> 4;

  __shared__ float hs[64][36];
  __shared__ float wt[64][36];
  float acc[4][4] = {};
  const float* hbase = h_in + (size_t)(bt * 64) * NC;

  for (int kc = 0; kc < 2; kc++) {
    int k0 = ks * 64 + kc * 32;
    __syncthreads();
    for (int t = 0; t < 2; t++) {
      int idx = tid + t * 256;
      int row = idx >> 3, kk4 = idx & 7;
      *(float4*)&hs[row][kk4 * 4] =
          *(const float4*)(hbase + (size_t)row * NC + k0 + kk4 * 4);
      int wrow = ct * 64 + row;
      *(float4*)&wt[row][kk4 * 4] =
          *(const float4*)(w1 + (size_t)wrow * NC + k0 + kk4 * 4);
    }
    __syncthreads();
#pragma unroll
    for (int kk4 = 0; kk4 < 8; kk4++) {
      float4 hv[4], wv[4];
#pragma unroll
      for (int i = 0; i < 4; i++) hv[i] = *(float4*)&hs[tb * 4 + i][kk4 * 4];
#pragma unroll
      for (int j = 0; j < 4; j++) wv[j] = *(float4*)&wt[tn + 16 * j][kk4 * 4];
#pragma unroll
      for (int i = 0; i < 4; i++)
#pragma unroll
        for (int j = 0; j < 4; j++)
          acc[i][j] += hv[i].x * wv[j].x + hv[i].y * wv[j].y +
                       hv[i].z * wv[j].z + hv[i].w * wv[j].w;
    }
  }
#pragma unroll
  for (int i = 0; i < 4; i++) {
    int b = bt * 64 + tb * 4 + i;
#pragma unroll
    for (int j = 0; j < 4; j++) {
      int cidx = ct * 64 + tn + 16 * j;
      Hpart[((size_t)ks * NB + b) * NC + cidx] = acc[i][j];
    }
  }
}

// ---------------------------------------------------------------------------
// Kernel 4: 16-pixel autoregressive block (register version, 8-partial sum).
// ---------------------------------------------------------------------------
__global__ __launch_bounds__(64) void pixel_kernel(
    const float* __restrict__ WD, const float* __restrict__ A0v,
    const float* __restrict__ Hpart, const float* __restrict__ w2,
    const float* __restrict__ b2, float* __restrict__ u_cur,
    int* __restrict__ v_cur, float* __restrict__ out_soft,
    float* __restrict__ out_u, float* __restrict__ out_v,
    int si, int sj, int t_base) {
  int b = blockIdx.x, lane = threadIdx.x;
  __shared__ float gum[32];

  int widx = (lane < 49) ? lane : 48;
  int vv = v_cur[b * 256 + (si + 1 + widx / 7) * 16 + (sj + 1 + widx % 7)];
  unsigned long long mask = __ballot((lane < 49) && (vv != 0));

  if (lane < 32) {
    int t = t_base + (lane >> 1);
    uint32_t sk0 = SUBKEYS.v[2 * t], sk1 = SUBKEYS.v[2 * t + 1];
    uint32_t bits;
#if PARTITIONABLE
    TFOut o = tf2x32(sk0, sk1, 0u, (uint32_t)(2 * b + (lane & 1)));
    bits = o.a ^ o.b;
#else
    uint32_t f = (uint32_t)(2 * b + (lane & 1));
    if (f < 256u) { TFOut o = tf2x32(sk0, sk1, f, f + 256u); bits = o.a; }
    else          { TFOut o = tf2x32(sk0, sk1, f - 256u, f); bits = o.b; }
#endif
    gum[lane] = gumbel_from_bits(bits);
  }

  float wdreg[NFS][8];
#pragma unroll
  for (int n = 0; n < NFS; n++)
#pragma unroll
    for (int r = 0; r < 8; r++) wdreg[n][r] = WD[n * NC + lane + 64 * r];

  float w2r0[8], w2r1[8];
#pragma unroll
  for (int r = 0; r < 8; r++) {
    w2r0[r] = w2[lane + 64 * r];
    w2r1[r] = w2[NC + lane + 64 * r];
  }
  double b20 = (double)b2[0], b21 = (double)b2[1];

  float base[8];
#pragma unroll
  for (int r = 0; r < 8; r++) {
    int c = lane + 64 * r;
    float v = A0v[c];
#pragma unroll
    for (int ks = 0; ks < 8; ks++) v += Hpart[((size_t)ks * NB + b) * NC + c];
    base[r] = v;
  }
  __syncthreads();

#pragma unroll 1
  for (int ii = 0; ii < 4; ii++) {
#pragma unroll 1
    for (int jj = 0; jj < 4; jj++) {
      int bofs = ii * 7 + jj;
      float acc[8];
#pragma unroll
      for (int r = 0; r < 8; r++) acc[r] = base[r];
#pragma unroll
      for (int n = 0; n < NFS; n++) {
        const int OFF = (n / 4) * 7 + (n % 4);
        float pf = (float)((unsigned)((mask >> (bofs + OFF)) & 1ull));
#pragma unroll
        for (int r = 0; r < 8; r++) acc[r] = fmaf(pf, wdreg[n][r], acc[r]);
      }
      double d0 = 0.0, d1 = 0.0;
#pragma unroll
      for (int r = 0; r < 8; r++) {
        float z = fmaxf(acc[r], 0.0f);
        d0 += (double)z * (double)w2r0[r];
        d1 += (double)z * (double)w2r1[r];
      }
#pragma unroll
      for (int off = 32; off > 0; off >>= 1) {
        d0 += __shfl_xor(d0, off, 64);
        d1 += __shfl_xor(d1, off, 64);
      }
      float r0 = (float)(d0 + b20);
      float r1 = (float)(d1 + b21);
      float m = fmaxf(r0, r1);
      float s0 = r0 - m, s1 = r1 - m;
      float lse = logf(expf(s0) + expf(s1));
      float l0 = s0 - lse, l1 = s1 - lse;
      int pidx = ii * 4 + jj;
      float a0 = l0 + gum[2 * pidx];
      float a1 = l1 + gum[2 * pidx + 1];
      int samp = (a1 > a0) ? 1 : 0;
      int tbit = bofs + 24;
      mask = (mask & ~(1ull << tbit)) | ((unsigned long long)samp << tbit);
      if (lane == 0) {
        int pr = si + ii + 4, pc = sj + jj + 4;
        size_t so = ((size_t)(b * 16 + pr) * 16 + pc) * 2;
        out_soft[so] = l0;
        out_soft[so + 1] = l1;
        int po = b * 256 + pr * 16 + pc;
        float fs = (float)samp;
        u_cur[po] = fs;
        v_cur[po] = samp;
        out_u[po] = fs;
        out_v[po] = fs;
      }
    }
  }
}

// ---------------------------------------------------------------------------
// Host-side launch sequence
// ---------------------------------------------------------------------------
extern "C" void kernel_launch(void* const* d_in, const int* in_sizes, int n_in,
                              void* d_out, int out_size, void* d_ws,
                              size_t ws_size, hipStream_t stream) {
  (void)in_sizes; (void)n_in; (void)out_size; (void)ws_size;
  const float* u_in = (const float*)d_in[0];
  const int*   v_in = (const int*)d_in[1];
  const float* emb  = (const float*)d_in[2];
  const float* w1   = (const float*)d_in[3];
  const float* b1   = (const float*)d_in[4];
  const float* w2   = (const float*)d_in[5];
  const float* b2   = (const float*)d_in[6];
  const float* wih  = (const float*)d_in[7];
  const float* whh  = (const float*)d_in[8];
  const float* bih  = (const float*)d_in[9];
  const float* bhh  = (const float*)d_in[10];

  float* ws = (float*)d_ws;
  const size_t HP = (size_t)3 * NB * NC;           // 393216: h parity stride
  float* h0buf = ws;                               // [2][3][NB][NC]
  float* cbuf  = h0buf + 2 * HP;                   // [3][NB][NC]
  float* Hpart = cbuf + (size_t)3 * NB * NC;       // [8][NB][NC]
  float* WDp   = Hpart + (size_t)8 * NB * NC;      // [15][NC]
  float* A0v   = WDp + NFS * NC;                   // [NC]
  float* u_cur = A0v + NC;                         // [NB][16][16]
  int*   v_cur = (int*)(u_cur + NB * NL * NL);     // [NB][16][16]
  unsigned short* Ahi = (unsigned short*)(v_cur + NB * NL * NL); // [2][768][512]
  unsigned short* Alo = Ahi + (size_t)2 * 768 * 512;             // [2][768][512]
  unsigned short* Bhi = Alo + (size_t)2 * 768 * 512;             // [2048][512]
  unsigned short* Blo = Bhi + (size_t)2048 * 512;                // [2048][512]
  const size_t APAR = (size_t)768 * 512;           // parity stride (shorts)

  float* out_soft = (float*)d_out;                 // [NB][16][16][2]
  float* out_u = out_soft + NB * NL * NL * 2;      // [NB][16][16]
  float* out_v = out_u + NB * NL * NL;             // [NB][16][16]

  setup_kernel<<<dim3(4096), dim3(256), 0, stream>>>(
      u_in, v_in, h0buf, cbuf, u_cur, v_cur, out_soft, out_u, out_v,
      (unsigned int*)Ahi);
  split_w_kernel<<<dim3(4096), dim3(256), 0, stream>>>(whh, Bhi, Blo);
  wd_kernel<<<dim3(16), dim3(256), 0, stream>>>(emb, w1, b1, WDp, A0v);

  for (int k = 0; k < 9; k++) {
    if (k > 0) {
      int e = k - 1;
      int col0 = (e % 3 == 0) ? 4 : ((e % 3 == 1) ? 8 : 0);
      int rp = e & 1, wp = rp ^ 1;
      lstm_fused2_kernel<<<dim3(768), dim3(256), 0, stream>>>(
          Ahi + (size_t)rp * APAR, Alo + (size_t)rp * APAR,
          Ahi + (size_t)wp * APAR, Alo + (size_t)wp * APAR,
          Bhi, Blo, wih, u_cur, bih, bhh, cbuf,
          h0buf + (size_t)wp * HP, col0);
    }
    w1h0_kernel<<<dim3(256), dim3(256), 0, stream>>>(
        h0buf + (size_t)(k & 1) * HP + (size_t)(k / 3) * NB * NC, w1, Hpart);
    pixel_kernel<<<dim3(256), dim3(64), 0, stream>>>(
        WDp, A0v, Hpart, w2, b2, u_cur, v_cur, out_soft, out_u, out_v,
        (k / 3) * 4, (k % 3) * 4, k * 16);
  }
}